// Round 5
// baseline (737.413 us; speedup 1.0000x reference)
//
#include <hip/hip_runtime.h>
#include <math.h>

#define NN      8192
#define DIM     512      // IN_DIM == H*HID
#define NHEAD   8
#define HID     64
#define NE      262144
#define NE_HALF 131072
#define TOPK    10
#define NEGV    -9e15f
#define MAXDEG  512

typedef __attribute__((ext_vector_type(8))) short short8;
typedef __attribute__((ext_vector_type(4))) float f32x4;

__device__ __forceinline__ float bf2f(unsigned int h) {
    return __uint_as_float(h << 16);
}
__device__ __forceinline__ unsigned short f2bf(float x) {
    unsigned int u = __float_as_uint(x);
    unsigned int r = (u + 0x7fff + ((u >> 16) & 1)) >> 16;   // RNE
    return (unsigned short)r;
}

// ---------------- split fp32 -> (hi, lo) bf16 ----------------
__global__ __launch_bounds__(256) void split_feat(const float* __restrict__ X,
                                                  unsigned short* __restrict__ H,
                                                  unsigned short* __restrict__ L) {
    int i = blockIdx.x * 256 + threadIdx.x;           // over float4s
    float4 v = ((const float4*)X)[i];
    unsigned short h0 = f2bf(v.x), h1 = f2bf(v.y), h2 = f2bf(v.z), h3 = f2bf(v.w);
    ushort4 hv; hv.x = h0; hv.y = h1; hv.z = h2; hv.w = h3;
    ushort4 lv;
    lv.x = f2bf(v.x - bf2f(h0));
    lv.y = f2bf(v.y - bf2f(h1));
    lv.z = f2bf(v.z - bf2f(h2));
    lv.w = f2bf(v.w - bf2f(h3));
    ((ushort4*)H)[i] = hv;
    ((ushort4*)L)[i] = lv;
}

// W[512][512] fp32 -> transposed split Th/Tl [n][k] bf16
__global__ __launch_bounds__(256) void split_w(const float* __restrict__ W,
                                               unsigned short* __restrict__ Th,
                                               unsigned short* __restrict__ Tl) {
    __shared__ float t[32][33];
    int k0 = blockIdx.y * 32, n0 = blockIdx.x * 32;
    int tx = threadIdx.x & 31, ty = threadIdx.x >> 5;   // ty 0..7
    #pragma unroll
    for (int i = 0; i < 4; i++)
        t[ty + 8 * i][tx] = W[(size_t)(k0 + ty + 8 * i) * DIM + n0 + tx];
    __syncthreads();
    #pragma unroll
    for (int i = 0; i < 4; i++) {
        float x = t[tx][ty + 8 * i];
        unsigned short h = f2bf(x);
        size_t off = (size_t)(n0 + ty + 8 * i) * DIM + k0 + tx;
        Th[off] = h;
        Tl[off] = f2bf(x - bf2f(h));
    }
}

// ---------------- MFMA GEMM: C = (Ah+Al) @ (Bh+Bl)^T, 3-pass split-bf16 ----
__global__ __launch_bounds__(256) void gemm_mfma(const unsigned short* __restrict__ Ah,
                                                 const unsigned short* __restrict__ Al,
                                                 const unsigned short* __restrict__ Bh,
                                                 const unsigned short* __restrict__ Bl,
                                                 unsigned short* __restrict__ Ch,
                                                 unsigned short* __restrict__ Cl) {
    __shared__ unsigned short As[128][32];   // 8 KB
    __shared__ unsigned short Bs[128][32];   // 8 KB
    const int bm = blockIdx.y * 128;
    const int bn = blockIdx.x * 128;
    const int tid = threadIdx.x;
    const int lane = tid & 63;
    const int wave = tid >> 6;
    const int wm = (wave >> 1) * 64, wn = (wave & 1) * 64;
    const int fr = lane & 15, fq = lane >> 4;
    const int sr = tid >> 2, sc = (tid & 3) * 8;
    f32x4 acc[4][4] = {};
    const unsigned short* Ap[3] = { Ah, Al, Ah };
    const unsigned short* Bp[3] = { Bh, Bh, Bl };
    for (int p = 0; p < 3; p++) {
        const unsigned short* Ag = Ap[p] + (size_t)(bm + sr) * DIM + sc;
        const unsigned short* Bg = Bp[p] + (size_t)(bn + sr) * DIM + sc;
        for (int kb = 0; kb < DIM; kb += 32) {
            __syncthreads();
            __builtin_amdgcn_global_load_lds(
                (const __attribute__((address_space(1))) void*)(Ag + kb),
                (__attribute__((address_space(3))) void*)(&As[sr][sc]), 16, 0, 0);
            __builtin_amdgcn_global_load_lds(
                (const __attribute__((address_space(1))) void*)(Ag + (size_t)64 * DIM + kb),
                (__attribute__((address_space(3))) void*)(&As[sr + 64][sc]), 16, 0, 0);
            __builtin_amdgcn_global_load_lds(
                (const __attribute__((address_space(1))) void*)(Bg + kb),
                (__attribute__((address_space(3))) void*)(&Bs[sr][sc]), 16, 0, 0);
            __builtin_amdgcn_global_load_lds(
                (const __attribute__((address_space(1))) void*)(Bg + (size_t)64 * DIM + kb),
                (__attribute__((address_space(3))) void*)(&Bs[sr + 64][sc]), 16, 0, 0);
            __syncthreads();
            short8 af[4], bfv[4];
            #pragma unroll
            for (int i = 0; i < 4; i++)
                af[i] = *(const short8*)&As[wm + i * 16 + fr][fq * 8];
            #pragma unroll
            for (int i = 0; i < 4; i++)
                bfv[i] = *(const short8*)&Bs[wn + i * 16 + fr][fq * 8];
            #pragma unroll
            for (int mi = 0; mi < 4; mi++)
                #pragma unroll
                for (int ni = 0; ni < 4; ni++)
                    acc[mi][ni] = __builtin_amdgcn_mfma_f32_16x16x32_bf16(
                        af[mi], bfv[ni], acc[mi][ni], 0, 0, 0);
        }
    }
    #pragma unroll
    for (int mi = 0; mi < 4; mi++)
        #pragma unroll
        for (int ni = 0; ni < 4; ni++)
            #pragma unroll
            for (int r = 0; r < 4; r++) {
                int row = bm + wm + mi * 16 + fq * 4 + r;
                int col = bn + wn + ni * 16 + fr;
                float v = acc[mi][ni][r];
                unsigned short h = f2bf(v);
                size_t off = (size_t)row * DIM + col;
                Ch[off] = h;
                Cl[off] = f2bf(v - bf2f(h));
            }
}

// ---------------- CSR by src ----------------
__global__ __launch_bounds__(256) void count_src(const int* __restrict__ src, int* counts) {
    int j = blockIdx.x * 256 + threadIdx.x;
    atomicAdd(&counts[src[j]], 1);
}

__global__ __launch_bounds__(256) void scan_offs(const int* __restrict__ counts,
                                                 int* __restrict__ offs, int* __restrict__ cur) {
    __shared__ int part[256];
    int t = threadIdx.x;
    int base = t * 32;
    int s = 0;
    for (int i = 0; i < 32; i++) s += counts[base + i];
    part[t] = s;
    __syncthreads();
    if (t == 0) {
        int run = 0;
        for (int i = 0; i < 256; i++) { int v = part[i]; part[i] = run; run += v; }
        offs[NN] = run;
    }
    __syncthreads();
    int run = part[t];
    for (int i = 0; i < 32; i++) {
        offs[base + i] = run;
        cur[base + i] = run;
        run += counts[base + i];
    }
}

__global__ __launch_bounds__(256) void scatter_src(const int* __restrict__ src,
                                                   int* cur, int* __restrict__ eid) {
    int j = blockIdx.x * 256 + threadIdx.x;
    int p = atomicAdd(&cur[src[j]], 1);
    eid[p] = j;
}

// ---------------- FUSED conv: dots + top-T threshold + softmax + aggregate --
// Block per node n (src-CSR). Locality theorem: node n's in-edge mask is
// exactly row n's own threshold decisions (dst[rev(j)]=src[j]=n), and
// e[rev(j)]==e[j] (dot symmetry) -> everything is block-local.
__global__ __launch_bounds__(256) void conv_fused(const unsigned short* __restrict__ Ch,
                                                  const unsigned short* __restrict__ Cl,
                                                  const int* __restrict__ offs,
                                                  const int* __restrict__ eid,
                                                  const int* __restrict__ dst,
                                                  const float* __restrict__ trans,
                                                  unsigned short* __restrict__ zb) {
    int n = blockIdx.x;
    int s0 = offs[n];
    int d = offs[n + 1] - s0;
    if (d > MAXDEG) d = MAXDEG;
    __shared__ float se[MAXDEG][NHEAD];        // 16 KB: logits -> weights
    __shared__ int   sdst[MAXDEG];
    __shared__ float sval[MAXDEG];             // coalesce input (A values)
    __shared__ float svc[MAXDEG];              // coalesced sums
    __shared__ unsigned char lead[MAXDEG];
    __shared__ unsigned char skeep[MAXDEG];
    __shared__ float pos[MAXDEG];
    __shared__ float thr_s;
    __shared__ float sm[NHEAD], ss[NHEAD];
    const int tid = threadIdx.x;
    const int wave = tid >> 6, lane = tid & 63;

    // ---- stage A: gather dst rows once, split-precision dots ----
    const uint4* ph = (const uint4*)(Ch + (size_t)n * DIM);
    const uint4* pl = (const uint4*)(Cl + (size_t)n * DIM);
    uint4 hv = ph[lane], lv = pl[lane];
    float a[8];
    a[0] = bf2f(hv.x & 0xffffu) + bf2f(lv.x & 0xffffu);
    a[1] = bf2f(hv.x >> 16)     + bf2f(lv.x >> 16);
    a[2] = bf2f(hv.y & 0xffffu) + bf2f(lv.y & 0xffffu);
    a[3] = bf2f(hv.y >> 16)     + bf2f(lv.y >> 16);
    a[4] = bf2f(hv.z & 0xffffu) + bf2f(lv.z & 0xffffu);
    a[5] = bf2f(hv.z >> 16)     + bf2f(lv.z >> 16);
    a[6] = bf2f(hv.w & 0xffffu) + bf2f(lv.w & 0xffffu);
    a[7] = bf2f(hv.w >> 16)     + bf2f(lv.w >> 16);
    for (int i = wave; i < d; i += 4) {
        int j = eid[s0 + i];
        int dj = dst[j];
        const uint4* qh = (const uint4*)(Ch + (size_t)dj * DIM);
        const uint4* ql = (const uint4*)(Cl + (size_t)dj * DIM);
        uint4 bh = qh[lane], bl = ql[lane];
        float p;
        p  = a[0] * (bf2f(bh.x & 0xffffu) + bf2f(bl.x & 0xffffu));
        p += a[1] * (bf2f(bh.x >> 16)     + bf2f(bl.x >> 16));
        p += a[2] * (bf2f(bh.y & 0xffffu) + bf2f(bl.y & 0xffffu));
        p += a[3] * (bf2f(bh.y >> 16)     + bf2f(bl.y >> 16));
        p += a[4] * (bf2f(bh.z & 0xffffu) + bf2f(bl.z & 0xffffu));
        p += a[5] * (bf2f(bh.z >> 16)     + bf2f(bl.z >> 16));
        p += a[6] * (bf2f(bh.w & 0xffffu) + bf2f(bl.w & 0xffffu));
        p += a[7] * (bf2f(bh.w >> 16)     + bf2f(bl.w >> 16));
        p += __shfl_xor(p, 1);
        p += __shfl_xor(p, 2);
        p += __shfl_xor(p, 4);           // per-head sums (head = lane>>3)
        if ((lane & 7) == 0) se[i][lane >> 3] = p;
        p += __shfl_xor(p, 8);
        p += __shfl_xor(p, 16);
        p += __shfl_xor(p, 32);          // full 512-dim sum
        if (lane == 0) { sdst[i] = dj; sval[i] = trans[j] * p; }
    }
    __syncthreads();

    // ---- stage B: coalesce duplicates + row top-T threshold ----
    for (int i = tid; i < d; i += 256) {
        int c = sdst[i];
        float sum = 0.f;
        bool leader = true;
        for (int k = 0; k < d; k++) {
            if (sdst[k] == c) {
                sum += sval[k];
                if (k < i) leader = false;
            }
        }
        svc[i] = sum;
        lead[i] = leader ? 1 : 0;
    }
    __syncthreads();
    if (tid == 0) {
        int p = 0;
        for (int i = 0; i < d; i++)
            if (lead[i] && svc[i] > 0.f) pos[p++] = svc[i];
        float thr = 0.f;
        if (p >= TOPK) {
            for (int t = 0; t < TOPK; t++) {
                int mi = 0; float mv = -1e30f;
                for (int i = 0; i < p; i++)
                    if (pos[i] > mv) { mv = pos[i]; mi = i; }
                thr = mv;
                pos[mi] = -1e30f;
            }
        }
        thr_s = thr;
    }
    __syncthreads();
    float thr = thr_s;
    for (int i = tid; i < d; i += 256)
        skeep[i] = (svc[i] >= thr) ? 1 : 0;
    __syncthreads();

    // ---- stage C: per-head masked softmax over in-edges (e symmetric) ----
    if (tid < NHEAD) {
        int h = tid;
        float m = -INFINITY;
        for (int i = 0; i < d; i++) {
            float x = skeep[i] ? se[i][h] : NEGV;
            m = fmaxf(m, x);
        }
        float s = 0.f;
        for (int i = 0; i < d; i++) {
            float x = skeep[i] ? se[i][h] : NEGV;
            s += expf(x - m);
        }
        sm[h] = m; ss[h] = s;
    }
    __syncthreads();
    for (int i = tid; i < d * NHEAD; i += 256) {
        int ii = i >> 3, h = i & 7;
        float x = skeep[ii] ? se[ii][h] : NEGV;
        se[ii][h] = expf(x - sm[h]) / ss[h];
    }
    __syncthreads();

    // ---- stage D: weighted sum (rows L2-hot from stage A) + ELU ----
    int c0 = tid * 2;
    int h = c0 >> 6;
    float acc0 = 0.f, acc1 = 0.f;
    for (int i = 0; i < d; i++) {
        const unsigned short* row = Ch + (size_t)sdst[i] * DIM;
        unsigned int v = *(const unsigned int*)(row + c0);
        float w = se[i][h];
        acc0 += w * bf2f(v & 0xffffu);
        acc1 += w * bf2f(v >> 16);
    }
    acc0 = acc0 > 0.f ? acc0 : expf(acc0) - 1.f;   // elu
    acc1 = acc1 > 0.f ? acc1 : expf(acc1) - 1.f;
    zb[(size_t)n * DIM + c0] = f2bf(acc0);
    zb[(size_t)n * DIM + c0 + 1] = f2bf(acc1);
}

// ---------------- semantic attention scores (tiled GEMM + fused tanh) -------
#define SBM 64
#define SBN 128
#define SBK 32

__global__ __launch_bounds__(256) void sem_scores2(const unsigned short* __restrict__ z0,
                                                   const unsigned short* __restrict__ z1,
                                                   const float* __restrict__ w1,
                                                   const float* __restrict__ b1,
                                                   const float* __restrict__ w2,
                                                   float* wsum) {
    const unsigned short* Z = blockIdx.y ? z1 : z0;
    const int bm = blockIdx.x * SBM;
    const int tid = threadIdx.x;
    const int tx = tid & 15, ty = tid >> 4;
    __shared__ float Zs[SBK][SBM + 1];
    __shared__ float Ws[SBK][SBN + 1];
    float acc[4][8] = {};
    for (int kb = 0; kb < DIM; kb += SBK) {
        #pragma unroll
        for (int it = 0; it < 2; it++) {
            int r = (tid >> 3) + it * 32;
            int c = (tid & 7) * 4;
            const unsigned short* p = Z + (size_t)(bm + r) * DIM + kb + c;
            unsigned int v0 = *(const unsigned int*)(p);
            unsigned int v1 = *(const unsigned int*)(p + 2);
            Zs[c][r]     = bf2f(v0 & 0xffffu);
            Zs[c + 1][r] = bf2f(v0 >> 16);
            Zs[c + 2][r] = bf2f(v1 & 0xffffu);
            Zs[c + 3][r] = bf2f(v1 >> 16);
        }
        #pragma unroll
        for (int it = 0; it < 4; it++) {
            int k = (tid >> 5) + it * 8;
            int n = (tid & 31) * 4;
            float4 v = *(const float4*)(w1 + (size_t)(kb + k) * SBN + n);
            Ws[k][n] = v.x; Ws[k][n + 1] = v.y; Ws[k][n + 2] = v.z; Ws[k][n + 3] = v.w;
        }
        __syncthreads();
        #pragma unroll
        for (int k = 0; k < SBK; k++) {
            float a[4], b[8];
            #pragma unroll
            for (int i = 0; i < 4; i++) a[i] = Zs[k][ty * 4 + i];
            #pragma unroll
            for (int j = 0; j < 8; j++) b[j] = Ws[k][tx * 8 + j];
            #pragma unroll
            for (int i = 0; i < 4; i++)
                #pragma unroll
                for (int j = 0; j < 8; j++) acc[i][j] += a[i] * b[j];
        }
        __syncthreads();
    }
    float local = 0.f;
    #pragma unroll
    for (int j = 0; j < 8; j++) {
        int col = tx * 8 + j;
        float bb = b1[col], ww = w2[col];
        #pragma unroll
        for (int i = 0; i < 4; i++)
            local += tanhf(acc[i][j] + bb) * ww;
    }
    __shared__ float red[256];
    red[tid] = local;
    __syncthreads();
    for (int s = 128; s > 0; s >>= 1) {
        if (tid < s) red[tid] += red[tid + s];
        __syncthreads();
    }
    if (tid == 0) atomicAdd(&wsum[blockIdx.y], red[0]);
}

// ---------------- final: beta-weighted combine + linear ----------------
__global__ __launch_bounds__(256) void final_out(const unsigned short* __restrict__ z0,
                                                 const unsigned short* __restrict__ z1,
                                                 const float* __restrict__ wsum,
                                                 const float* __restrict__ lin_w,
                                                 const float* __restrict__ lin_b,
                                                 float* __restrict__ out) {
    int idx = blockIdx.x * 256 + threadIdx.x;   // 24576 threads
    int n = idx / 3, o = idx - n * 3;
    float w0 = wsum[0] * (1.0f / NN), w1v = wsum[1] * (1.0f / NN);
    float mx = fmaxf(w0, w1v);
    float e0 = expf(w0 - mx), e1 = expf(w1v - mx);
    float beta0 = e0 / (e0 + e1), beta1 = e1 / (e0 + e1);
    const unsigned short* p0 = z0 + (size_t)n * DIM;
    const unsigned short* p1 = z1 + (size_t)n * DIM;
    float acc = 0.f;
    for (int dd = 0; dd < DIM; dd++)
        acc += (beta0 * bf2f(p0[dd]) + beta1 * bf2f(p1[dd])) * lin_w[dd * 3 + o];
    out[idx] = acc + lin_b[o];
}

// ---------------- launch ----------------
extern "C" void kernel_launch(void* const* d_in, const int* in_sizes, int n_in,
                              void* d_out, int out_size, void* d_ws, size_t ws_size,
                              hipStream_t stream) {
    const float* feat = (const float*)d_in[0];
    const int*   srcp[2]   = { (const int*)d_in[1], (const int*)d_in[4] };
    const int*   dstp[2]   = { (const int*)d_in[2], (const int*)d_in[5] };
    const float* transp[2] = { (const float*)d_in[3], (const float*)d_in[6] };
    const float* fcw[2]    = { (const float*)d_in[7], (const float*)d_in[8] };
    const float* sem_w1 = (const float*)d_in[9];
    const float* sem_b1 = (const float*)d_in[10];
    const float* sem_w2 = (const float*)d_in[11];
    const float* lin_w  = (const float*)d_in[12];
    const float* lin_b  = (const float*)d_in[13];
    float* out = (float*)d_out;

    char* ws = (char*)d_ws;
    const size_t MB = 1 << 20;
    if (ws_size < 52 * MB) return;
    unsigned short* Ch    = (unsigned short*)(ws);               //  8 MB
    unsigned short* Cl    = (unsigned short*)(ws + 8 * MB);      //  8 MB
    unsigned short* z0    = (unsigned short*)(ws + 16 * MB);     //  8 MB
    unsigned short* z1    = (unsigned short*)(ws + 24 * MB);     //  8 MB
    unsigned short* fH    = (unsigned short*)(ws + 32 * MB);     //  8 MB
    unsigned short* fL    = (unsigned short*)(ws + 40 * MB);     //  8 MB
    int*            eid   = (int*)  (ws + 48 * MB);              //  1 MB
    unsigned short* BhT   = (unsigned short*)(ws + 49 * MB);     // 512 KB
    unsigned short* BlT   = (unsigned short*)(ws + 49 * MB + 524288);
    int*            counts= (int*)  (ws + 50 * MB);              // 32 KB
    int*            offs  = (int*)  (ws + 50 * MB + 32768);      // 33 KB
    int*            cur   = (int*)  (ws + 50 * MB + 32768 + 36864);
    float*          wsum  = (float*)(ws + 50 * MB + 32768 + 36864 + 32768);

    split_feat<<<(NN * DIM / 4) / 256, 256, 0, stream>>>(feat, fH, fL);
    for (int c = 0; c < 2; c++) {
        unsigned short* z = c ? z1 : z0;
        hipMemsetAsync(counts, 0, NN * sizeof(int), stream);
        count_src<<<NE / 256, 256, 0, stream>>>(srcp[c], counts);
        scan_offs<<<1, 256, 0, stream>>>(counts, offs, cur);
        scatter_src<<<NE / 256, 256, 0, stream>>>(srcp[c], cur, eid);
        split_w<<<dim3(16, 16), 256, 0, stream>>>(fcw[c], BhT, BlT);
        gemm_mfma<<<dim3(4, 64), 256, 0, stream>>>(fH, fL, BhT, BlT, Ch, Cl);
        conv_fused<<<NN, 256, 0, stream>>>(Ch, Cl, offs, eid, dstp[c], transp[c], z);
    }
    hipMemsetAsync(wsum, 0, 2 * sizeof(float), stream);
    sem_scores2<<<dim3(NN / SBM, 2), 256, 0, stream>>>(z0, z1, sem_w1, sem_b1, sem_w2, wsum);
    final_out<<<(NN * 3) / 256, 256, 0, stream>>>(z0, z1, wsum, lin_w, lin_b, out);
}

// Round 6
// 618.153 us; speedup vs baseline: 1.1929x; 1.1929x over previous
//
#include <hip/hip_runtime.h>
#include <math.h>

#define NN      8192
#define DIM     512      // IN_DIM == H*HID
#define NHEAD   8
#define HID     64
#define NE      262144
#define NE_HALF 131072
#define CMASK   (NE_HALF - 1)      // canonical edge id = j & CMASK (graph symmetric)
#define TOPK    10
#define NEGV    -9e15f
#define MAXDEG  512

typedef __attribute__((ext_vector_type(8))) short short8;
typedef __attribute__((ext_vector_type(4))) float f32x4;

__device__ __forceinline__ float bf2f(unsigned int h) {
    return __uint_as_float(h << 16);
}
__device__ __forceinline__ unsigned short f2bf(float x) {
    unsigned int u = __float_as_uint(x);
    unsigned int r = (u + 0x7fff + ((u >> 16) & 1)) >> 16;   // RNE
    return (unsigned short)r;
}

// ---------------- split fp32 -> (hi, lo) bf16 ----------------
__global__ __launch_bounds__(256) void split_feat(const float* __restrict__ X,
                                                  unsigned short* __restrict__ H,
                                                  unsigned short* __restrict__ L) {
    int i = blockIdx.x * 256 + threadIdx.x;           // over float4s
    float4 v = ((const float4*)X)[i];
    unsigned short h0 = f2bf(v.x), h1 = f2bf(v.y), h2 = f2bf(v.z), h3 = f2bf(v.w);
    ushort4 hv; hv.x = h0; hv.y = h1; hv.z = h2; hv.w = h3;
    ushort4 lv;
    lv.x = f2bf(v.x - bf2f(h0));
    lv.y = f2bf(v.y - bf2f(h1));
    lv.z = f2bf(v.z - bf2f(h2));
    lv.w = f2bf(v.w - bf2f(h3));
    ((ushort4*)H)[i] = hv;
    ((ushort4*)L)[i] = lv;
}

// W[512][512] fp32 -> transposed split Th/Tl [n][k] bf16
__global__ __launch_bounds__(256) void split_w(const float* __restrict__ W,
                                               unsigned short* __restrict__ Th,
                                               unsigned short* __restrict__ Tl) {
    __shared__ float t[32][33];
    int k0 = blockIdx.y * 32, n0 = blockIdx.x * 32;
    int tx = threadIdx.x & 31, ty = threadIdx.x >> 5;   // ty 0..7
    #pragma unroll
    for (int i = 0; i < 4; i++)
        t[ty + 8 * i][tx] = W[(size_t)(k0 + ty + 8 * i) * DIM + n0 + tx];
    __syncthreads();
    #pragma unroll
    for (int i = 0; i < 4; i++) {
        float x = t[tx][ty + 8 * i];
        unsigned short h = f2bf(x);
        size_t off = (size_t)(n0 + ty + 8 * i) * DIM + k0 + tx;
        Th[off] = h;
        Tl[off] = f2bf(x - bf2f(h));
    }
}

// ---------------- MFMA GEMM: C = (Ah+Al) @ (Bh+Bl)^T, 3-pass split-bf16 ----
__global__ __launch_bounds__(256) void gemm_mfma(const unsigned short* __restrict__ Ah,
                                                 const unsigned short* __restrict__ Al,
                                                 const unsigned short* __restrict__ Bh,
                                                 const unsigned short* __restrict__ Bl,
                                                 unsigned short* __restrict__ Ch,
                                                 unsigned short* __restrict__ Cl) {
    __shared__ unsigned short As[128][32];   // 8 KB
    __shared__ unsigned short Bs[128][32];   // 8 KB
    const int bm = blockIdx.y * 128;
    const int bn = blockIdx.x * 128;
    const int tid = threadIdx.x;
    const int lane = tid & 63;
    const int wave = tid >> 6;
    const int wm = (wave >> 1) * 64, wn = (wave & 1) * 64;
    const int fr = lane & 15, fq = lane >> 4;
    const int sr = tid >> 2, sc = (tid & 3) * 8;
    f32x4 acc[4][4] = {};
    const unsigned short* Ap[3] = { Ah, Al, Ah };
    const unsigned short* Bp[3] = { Bh, Bh, Bl };
    for (int p = 0; p < 3; p++) {
        const unsigned short* Ag = Ap[p] + (size_t)(bm + sr) * DIM + sc;
        const unsigned short* Bg = Bp[p] + (size_t)(bn + sr) * DIM + sc;
        for (int kb = 0; kb < DIM; kb += 32) {
            __syncthreads();
            __builtin_amdgcn_global_load_lds(
                (const __attribute__((address_space(1))) void*)(Ag + kb),
                (__attribute__((address_space(3))) void*)(&As[sr][sc]), 16, 0, 0);
            __builtin_amdgcn_global_load_lds(
                (const __attribute__((address_space(1))) void*)(Ag + (size_t)64 * DIM + kb),
                (__attribute__((address_space(3))) void*)(&As[sr + 64][sc]), 16, 0, 0);
            __builtin_amdgcn_global_load_lds(
                (const __attribute__((address_space(1))) void*)(Bg + kb),
                (__attribute__((address_space(3))) void*)(&Bs[sr][sc]), 16, 0, 0);
            __builtin_amdgcn_global_load_lds(
                (const __attribute__((address_space(1))) void*)(Bg + (size_t)64 * DIM + kb),
                (__attribute__((address_space(3))) void*)(&Bs[sr + 64][sc]), 16, 0, 0);
            __syncthreads();
            short8 af[4], bfv[4];
            #pragma unroll
            for (int i = 0; i < 4; i++)
                af[i] = *(const short8*)&As[wm + i * 16 + fr][fq * 8];
            #pragma unroll
            for (int i = 0; i < 4; i++)
                bfv[i] = *(const short8*)&Bs[wn + i * 16 + fr][fq * 8];
            #pragma unroll
            for (int mi = 0; mi < 4; mi++)
                #pragma unroll
                for (int ni = 0; ni < 4; ni++)
                    acc[mi][ni] = __builtin_amdgcn_mfma_f32_16x16x32_bf16(
                        af[mi], bfv[ni], acc[mi][ni], 0, 0, 0);
        }
    }
    #pragma unroll
    for (int mi = 0; mi < 4; mi++)
        #pragma unroll
        for (int ni = 0; ni < 4; ni++)
            #pragma unroll
            for (int r = 0; r < 4; r++) {
                int row = bm + wm + mi * 16 + fq * 4 + r;
                int col = bn + wn + ni * 16 + fr;
                float v = acc[mi][ni][r];
                unsigned short h = f2bf(v);
                size_t off = (size_t)row * DIM + col;
                Ch[off] = h;
                Cl[off] = f2bf(v - bf2f(h));
            }
}

// ---------------- CSR by src ----------------
__global__ __launch_bounds__(256) void count_src(const int* __restrict__ src, int* counts) {
    int j = blockIdx.x * 256 + threadIdx.x;
    atomicAdd(&counts[src[j]], 1);
}

__global__ __launch_bounds__(256) void scan_offs(const int* __restrict__ counts,
                                                 int* __restrict__ offs, int* __restrict__ cur) {
    __shared__ int part[256];
    int t = threadIdx.x;
    int base = t * 32;
    int s = 0;
    for (int i = 0; i < 32; i++) s += counts[base + i];
    part[t] = s;
    __syncthreads();
    if (t == 0) {
        int run = 0;
        for (int i = 0; i < 256; i++) { int v = part[i]; part[i] = run; run += v; }
        offs[NN] = run;
    }
    __syncthreads();
    int run = part[t];
    for (int i = 0; i < 32; i++) {
        offs[base + i] = run;
        cur[base + i] = run;
        run += counts[base + i];
    }
}

__global__ __launch_bounds__(256) void scatter_src(const int* __restrict__ src,
                                                   int* cur, int* __restrict__ eid) {
    int j = blockIdx.x * 256 + threadIdx.x;
    int p = atomicAdd(&cur[src[j]], 1);
    eid[p] = j;
}

// ---------------- per-edge per-head dots + vals (CSR order, CANONICAL only) -
// e[jc][h], vals[jc] computed once per undirected edge (jc < NE_HALF);
// consumers index via j & CMASK (e/vals symmetric under reversal).
__global__ __launch_bounds__(256) void edge_dots_csr(const unsigned short* __restrict__ Ch,
                                                     const unsigned short* __restrict__ Cl,
                                                     const int* __restrict__ offs,
                                                     const int* __restrict__ eid,
                                                     const int* __restrict__ dst,
                                                     const float* __restrict__ trans,
                                                     float* __restrict__ e,
                                                     float* __restrict__ vals) {
    int n = blockIdx.x;
    int s0 = offs[n];
    int d = offs[n + 1] - s0;
    if (d <= 0) return;
    int wave = threadIdx.x >> 6, lane = threadIdx.x & 63;
    const uint4* ph = (const uint4*)(Ch + (size_t)n * DIM);
    const uint4* pl = (const uint4*)(Cl + (size_t)n * DIM);
    uint4 hv = ph[lane], lv = pl[lane];
    float a[8];
    a[0] = bf2f(hv.x & 0xffffu) + bf2f(lv.x & 0xffffu);
    a[1] = bf2f(hv.x >> 16)     + bf2f(lv.x >> 16);
    a[2] = bf2f(hv.y & 0xffffu) + bf2f(lv.y & 0xffffu);
    a[3] = bf2f(hv.y >> 16)     + bf2f(lv.y >> 16);
    a[4] = bf2f(hv.z & 0xffffu) + bf2f(lv.z & 0xffffu);
    a[5] = bf2f(hv.z >> 16)     + bf2f(lv.z >> 16);
    a[6] = bf2f(hv.w & 0xffffu) + bf2f(lv.w & 0xffffu);
    a[7] = bf2f(hv.w >> 16)     + bf2f(lv.w >> 16);
    for (int i = wave; i < d; i += 4) {
        int j = eid[s0 + i];
        if (j >= NE_HALF) continue;          // canonical copies only
        const uint4* qh = (const uint4*)(Ch + (size_t)dst[j] * DIM);
        const uint4* ql = (const uint4*)(Cl + (size_t)dst[j] * DIM);
        uint4 bh = qh[lane], bl = ql[lane];
        float p;
        p  = a[0] * (bf2f(bh.x & 0xffffu) + bf2f(bl.x & 0xffffu));
        p += a[1] * (bf2f(bh.x >> 16)     + bf2f(bl.x >> 16));
        p += a[2] * (bf2f(bh.y & 0xffffu) + bf2f(bl.y & 0xffffu));
        p += a[3] * (bf2f(bh.y >> 16)     + bf2f(bl.y >> 16));
        p += a[4] * (bf2f(bh.z & 0xffffu) + bf2f(bl.z & 0xffffu));
        p += a[5] * (bf2f(bh.z >> 16)     + bf2f(bl.z >> 16));
        p += a[6] * (bf2f(bh.w & 0xffffu) + bf2f(bl.w & 0xffffu));
        p += a[7] * (bf2f(bh.w >> 16)     + bf2f(bl.w >> 16));
        p += __shfl_xor(p, 1);
        p += __shfl_xor(p, 2);
        p += __shfl_xor(p, 4);           // per-head sums (head = lane>>3)
        if ((lane & 7) == 0) e[(size_t)j * NHEAD + (lane >> 3)] = p;
        p += __shfl_xor(p, 8);
        p += __shfl_xor(p, 16);
        p += __shfl_xor(p, 32);          // full 512-dim sum
        if (lane == 0) vals[j] = trans[j] * p;
    }
}

// ---------------- per-row coalesce + top-T threshold -> keep flags ----------
__global__ __launch_bounds__(128) void row_thresh(const int* __restrict__ offs,
                                                  const int* __restrict__ eid,
                                                  const int* __restrict__ dst,
                                                  const float* __restrict__ vals,
                                                  unsigned char* __restrict__ keep) {
    int r = blockIdx.x;
    int s0 = offs[r];
    int d = offs[r + 1] - s0;
    if (d > MAXDEG) d = MAXDEG;
    __shared__ int   sc[MAXDEG];
    __shared__ float sv[MAXDEG];
    __shared__ int   sj[MAXDEG];
    __shared__ float svc[MAXDEG];
    __shared__ unsigned char lead[MAXDEG];
    __shared__ float pos[MAXDEG];
    __shared__ float thr_s;
    for (int i = threadIdx.x; i < d; i += blockDim.x) {
        int j = eid[s0 + i];
        sj[i] = j; sc[i] = dst[j]; sv[i] = vals[j & CMASK];
    }
    __syncthreads();
    for (int i = threadIdx.x; i < d; i += blockDim.x) {
        int c = sc[i];
        float sum = 0.f;
        bool leader = true;
        for (int k = 0; k < d; k++) {
            if (sc[k] == c) {
                sum += sv[k];
                if (k < i) leader = false;
            }
        }
        svc[i] = sum;
        lead[i] = leader ? 1 : 0;
    }
    __syncthreads();
    if (threadIdx.x == 0) {
        int p = 0;
        for (int i = 0; i < d; i++)
            if (lead[i] && svc[i] > 0.f) pos[p++] = svc[i];
        float thr = 0.f;
        if (p >= TOPK) {
            for (int t = 0; t < TOPK; t++) {
                int mi = 0; float mv = -1e30f;
                for (int i = 0; i < p; i++)
                    if (pos[i] > mv) { mv = pos[i]; mi = i; }
                thr = mv;
                pos[mi] = -1e30f;
            }
        }
        thr_s = thr;
    }
    __syncthreads();
    float thr = thr_s;
    for (int i = threadIdx.x; i < d; i += blockDim.x)
        keep[sj[i]] = (svc[i] >= thr) ? 1 : 0;
}

// ---------------- edge softmax by dst + aggregation + ELU (bf16 reads) -----
// block per dst node n. In-edges of n are rev(j) for j in src-CSR[n];
// in-edge rev(j): source=dst[j], e[canon(j)] (symmetric), mask=keep[j].
__global__ __launch_bounds__(256) void aggregate(const int* __restrict__ offs,
                                                 const int* __restrict__ eid,
                                                 const int* __restrict__ dst,
                                                 const float* __restrict__ e,
                                                 const unsigned char* __restrict__ keep,
                                                 const unsigned short* __restrict__ fb,
                                                 unsigned short* __restrict__ zb) {
    int n = blockIdx.x;
    int s0 = offs[n];
    int d = offs[n + 1] - s0;
    if (d > MAXDEG) d = MAXDEG;
    __shared__ float sa[MAXDEG][NHEAD];  // 16 KB
    __shared__ int ssrc[MAXDEG];
    __shared__ float sm[NHEAD], ss[NHEAD];
    for (int i = threadIdx.x; i < d; i += blockDim.x) {
        int j = eid[s0 + i];
        ssrc[i] = dst[j];
        int kp = keep[j];
        const float* ep = e + (size_t)(j & CMASK) * NHEAD;
        #pragma unroll
        for (int h = 0; h < NHEAD; h++) sa[i][h] = kp ? ep[h] : NEGV;
    }
    __syncthreads();
    if (threadIdx.x < NHEAD) {
        int h = threadIdx.x;
        float m = -INFINITY;
        for (int i = 0; i < d; i++) m = fmaxf(m, sa[i][h]);
        float s = 0.f;
        for (int i = 0; i < d; i++) s += expf(sa[i][h] - m);
        sm[h] = m; ss[h] = s;
    }
    __syncthreads();
    for (int i = threadIdx.x; i < d * NHEAD; i += blockDim.x) {
        int ii = i >> 3, h = i & 7;
        sa[ii][h] = expf(sa[ii][h] - sm[h]) / ss[h];
    }
    __syncthreads();
    int c0 = threadIdx.x * 2;
    int h = c0 >> 6;
    float acc0 = 0.f, acc1 = 0.f;
    for (int i = 0; i < d; i++) {
        const unsigned short* row = fb + (size_t)ssrc[i] * DIM;
        unsigned int v = *(const unsigned int*)(row + c0);
        float a = sa[i][h];
        acc0 += a * bf2f(v & 0xffffu);
        acc1 += a * bf2f(v >> 16);
    }
    acc0 = acc0 > 0.f ? acc0 : expf(acc0) - 1.f;   // elu
    acc1 = acc1 > 0.f ? acc1 : expf(acc1) - 1.f;
    zb[(size_t)n * DIM + c0] = f2bf(acc0);
    zb[(size_t)n * DIM + c0 + 1] = f2bf(acc1);
}

// ---------------- semantic attention scores (tiled GEMM + fused tanh) -------
#define SBM 64
#define SBN 128
#define SBK 32

__global__ __launch_bounds__(256) void sem_scores2(const unsigned short* __restrict__ z0,
                                                   const unsigned short* __restrict__ z1,
                                                   const float* __restrict__ w1,
                                                   const float* __restrict__ b1,
                                                   const float* __restrict__ w2,
                                                   float* wsum) {
    const unsigned short* Z = blockIdx.y ? z1 : z0;
    const int bm = blockIdx.x * SBM;
    const int tid = threadIdx.x;
    const int tx = tid & 15, ty = tid >> 4;
    __shared__ float Zs[SBK][SBM + 1];
    __shared__ float Ws[SBK][SBN + 1];
    float acc[4][8] = {};
    for (int kb = 0; kb < DIM; kb += SBK) {
        #pragma unroll
        for (int it = 0; it < 2; it++) {
            int r = (tid >> 3) + it * 32;
            int c = (tid & 7) * 4;
            const unsigned short* p = Z + (size_t)(bm + r) * DIM + kb + c;
            unsigned int v0 = *(const unsigned int*)(p);
            unsigned int v1 = *(const unsigned int*)(p + 2);
            Zs[c][r]     = bf2f(v0 & 0xffffu);
            Zs[c + 1][r] = bf2f(v0 >> 16);
            Zs[c + 2][r] = bf2f(v1 & 0xffffu);
            Zs[c + 3][r] = bf2f(v1 >> 16);
        }
        #pragma unroll
        for (int it = 0; it < 4; it++) {
            int k = (tid >> 5) + it * 8;
            int n = (tid & 31) * 4;
            float4 v = *(const float4*)(w1 + (size_t)(kb + k) * SBN + n);
            Ws[k][n] = v.x; Ws[k][n + 1] = v.y; Ws[k][n + 2] = v.z; Ws[k][n + 3] = v.w;
        }
        __syncthreads();
        #pragma unroll
        for (int k = 0; k < SBK; k++) {
            float a[4], b[8];
            #pragma unroll
            for (int i = 0; i < 4; i++) a[i] = Zs[k][ty * 4 + i];
            #pragma unroll
            for (int j = 0; j < 8; j++) b[j] = Ws[k][tx * 8 + j];
            #pragma unroll
            for (int i = 0; i < 4; i++)
                #pragma unroll
                for (int j = 0; j < 8; j++) acc[i][j] += a[i] * b[j];
        }
        __syncthreads();
    }
    float local = 0.f;
    #pragma unroll
    for (int j = 0; j < 8; j++) {
        int col = tx * 8 + j;
        float bb = b1[col], ww = w2[col];
        #pragma unroll
        for (int i = 0; i < 4; i++)
            local += tanhf(acc[i][j] + bb) * ww;
    }
    __shared__ float red[256];
    red[tid] = local;
    __syncthreads();
    for (int s = 128; s > 0; s >>= 1) {
        if (tid < s) red[tid] += red[tid + s];
        __syncthreads();
    }
    if (tid == 0) atomicAdd(&wsum[blockIdx.y], red[0]);
}

// ---------------- final: beta-weighted combine + linear ----------------
__global__ __launch_bounds__(256) void final_out(const unsigned short* __restrict__ z0,
                                                 const unsigned short* __restrict__ z1,
                                                 const float* __restrict__ wsum,
                                                 const float* __restrict__ lin_w,
                                                 const float* __restrict__ lin_b,
                                                 float* __restrict__ out) {
    int idx = blockIdx.x * 256 + threadIdx.x;   // 24576 threads
    int n = idx / 3, o = idx - n * 3;
    float w0 = wsum[0] * (1.0f / NN), w1v = wsum[1] * (1.0f / NN);
    float mx = fmaxf(w0, w1v);
    float e0 = expf(w0 - mx), e1 = expf(w1v - mx);
    float beta0 = e0 / (e0 + e1), beta1 = e1 / (e0 + e1);
    const unsigned short* p0 = z0 + (size_t)n * DIM;
    const unsigned short* p1 = z1 + (size_t)n * DIM;
    float acc = 0.f;
    for (int dd = 0; dd < DIM; dd++)
        acc += (beta0 * bf2f(p0[dd]) + beta1 * bf2f(p1[dd])) * lin_w[dd * 3 + o];
    out[idx] = acc + lin_b[o];
}

// ---------------- launch ----------------
extern "C" void kernel_launch(void* const* d_in, const int* in_sizes, int n_in,
                              void* d_out, int out_size, void* d_ws, size_t ws_size,
                              hipStream_t stream) {
    const float* feat = (const float*)d_in[0];
    const int*   srcp[2]   = { (const int*)d_in[1], (const int*)d_in[4] };
    const int*   dstp[2]   = { (const int*)d_in[2], (const int*)d_in[5] };
    const float* transp[2] = { (const float*)d_in[3], (const float*)d_in[6] };
    const float* fcw[2]    = { (const float*)d_in[7], (const float*)d_in[8] };
    const float* sem_w1 = (const float*)d_in[9];
    const float* sem_b1 = (const float*)d_in[10];
    const float* sem_w2 = (const float*)d_in[11];
    const float* lin_w  = (const float*)d_in[12];
    const float* lin_b  = (const float*)d_in[13];
    float* out = (float*)d_out;

    char* ws = (char*)d_ws;
    const size_t MB = 1 << 20;
    if (ws_size < 56 * MB) return;
    unsigned short* Ch    = (unsigned short*)(ws);               //  8 MB
    unsigned short* Cl    = (unsigned short*)(ws + 8 * MB);      //  8 MB
    unsigned short* z0    = (unsigned short*)(ws + 16 * MB);     //  8 MB
    unsigned short* z1    = (unsigned short*)(ws + 24 * MB);     //  8 MB
    unsigned short* fH    = (unsigned short*)(ws + 32 * MB);     //  8 MB
    unsigned short* fL    = (unsigned short*)(ws + 40 * MB);     //  8 MB
    float*          e     = (float*)(ws + 48 * MB);              //  4 MB (NE_HALF*8)
    float*          vals  = (float*)(ws + 52 * MB);              // 512 KB (NE_HALF)
    int*            eid   = (int*)  (ws + 52 * MB + 1 * MB);     //  1 MB
    unsigned short* BhT   = (unsigned short*)(ws + 52 * MB + 2 * MB);  // 512 KB
    unsigned short* BlT   = (unsigned short*)(ws + 52 * MB + 2 * MB + 524288);
    unsigned char*  keep  = (unsigned char*)(ws + 55 * MB);      // 256 KB
    int*            counts= (int*)  (ws + 55 * MB + 262144);     // 32 KB
    int*            offs  = (int*)  (ws + 55 * MB + 262144 + 32768);  // 33 KB
    int*            cur   = (int*)  (ws + 55 * MB + 262144 + 32768 + 36864);
    float*          wsum  = (float*)(ws + 55 * MB + 262144 + 32768 + 36864 + 32768);

    split_feat<<<(NN * DIM / 4) / 256, 256, 0, stream>>>(feat, fH, fL);
    for (int c = 0; c < 2; c++) {
        unsigned short* z = c ? z1 : z0;
        hipMemsetAsync(counts, 0, NN * sizeof(int), stream);
        count_src<<<NE / 256, 256, 0, stream>>>(srcp[c], counts);
        scan_offs<<<1, 256, 0, stream>>>(counts, offs, cur);
        scatter_src<<<NE / 256, 256, 0, stream>>>(srcp[c], cur, eid);
        split_w<<<dim3(16, 16), 256, 0, stream>>>(fcw[c], BhT, BlT);
        gemm_mfma<<<dim3(4, 64), 256, 0, stream>>>(fH, fL, BhT, BlT, Ch, Cl);
        edge_dots_csr<<<NN, 256, 0, stream>>>(Ch, Cl, offs, eid, dstp[c], transp[c], e, vals);
        row_thresh<<<NN, 128, 0, stream>>>(offs, eid, dstp[c], vals, keep);
        aggregate<<<NN, 256, 0, stream>>>(offs, eid, dstp[c], e, keep, Ch, z);
    }
    hipMemsetAsync(wsum, 0, 2 * sizeof(float), stream);
    sem_scores2<<<dim3(NN / SBM, 2), 256, 0, stream>>>(z0, z1, sem_w1, sem_b1, sem_w2, wsum);
    final_out<<<(NN * 3) / 256, 256, 0, stream>>>(z0, z1, wsum, lin_w, lin_b, out);
}

// Round 7
// 570.300 us; speedup vs baseline: 1.2930x; 1.0839x over previous
//
#include <hip/hip_runtime.h>
#include <math.h>

#define NN      8192
#define DIM     512      // IN_DIM == H*HID
#define NHEAD   8
#define HID     64
#define NE      262144
#define NE_HALF 131072
#define CMASK   (NE_HALF - 1)      // canonical edge id = j & CMASK (graph symmetric)
#define TOPK    10
#define NEGV    -9e15f
#define MAXDEG  512

typedef __attribute__((ext_vector_type(8))) short short8;
typedef __attribute__((ext_vector_type(4))) float f32x4;

__device__ __forceinline__ float bf2f(unsigned int h) {
    return __uint_as_float(h << 16);
}
__device__ __forceinline__ unsigned short f2bf(float x) {
    unsigned int u = __float_as_uint(x);
    unsigned int r = (u + 0x7fff + ((u >> 16) & 1)) >> 16;   // RNE
    return (unsigned short)r;
}

// ---------------- split fp32 -> (hi, lo) bf16 ----------------
__global__ __launch_bounds__(256) void split_feat(const float* __restrict__ X,
                                                  unsigned short* __restrict__ H,
                                                  unsigned short* __restrict__ L) {
    int i = blockIdx.x * 256 + threadIdx.x;           // over float4s
    float4 v = ((const float4*)X)[i];
    unsigned short h0 = f2bf(v.x), h1 = f2bf(v.y), h2 = f2bf(v.z), h3 = f2bf(v.w);
    ushort4 hv; hv.x = h0; hv.y = h1; hv.z = h2; hv.w = h3;
    ushort4 lv;
    lv.x = f2bf(v.x - bf2f(h0));
    lv.y = f2bf(v.y - bf2f(h1));
    lv.z = f2bf(v.z - bf2f(h2));
    lv.w = f2bf(v.w - bf2f(h3));
    ((ushort4*)H)[i] = hv;
    ((ushort4*)L)[i] = lv;
}

// W[512][512] fp32 -> transposed split Th/Tl [n][k] bf16
__global__ __launch_bounds__(256) void split_w(const float* __restrict__ W,
                                               unsigned short* __restrict__ Th,
                                               unsigned short* __restrict__ Tl) {
    __shared__ float t[32][33];
    int k0 = blockIdx.y * 32, n0 = blockIdx.x * 32;
    int tx = threadIdx.x & 31, ty = threadIdx.x >> 5;   // ty 0..7
    #pragma unroll
    for (int i = 0; i < 4; i++)
        t[ty + 8 * i][tx] = W[(size_t)(k0 + ty + 8 * i) * DIM + n0 + tx];
    __syncthreads();
    #pragma unroll
    for (int i = 0; i < 4; i++) {
        float x = t[tx][ty + 8 * i];
        unsigned short h = f2bf(x);
        size_t off = (size_t)(n0 + ty + 8 * i) * DIM + k0 + tx;
        Th[off] = h;
        Tl[off] = f2bf(x - bf2f(h));
    }
}

// sem_w1[512][128] fp32 -> transposed split [128 cols][512 k] bf16 hi/lo
__global__ __launch_bounds__(256) void split_w1t(const float* __restrict__ W,
                                                 unsigned short* __restrict__ Th,
                                                 unsigned short* __restrict__ Tl) {
    __shared__ float t[32][33];
    int n0 = blockIdx.x * 32;      // cols (0..127)
    int k0 = blockIdx.y * 32;      // k    (0..511)
    int tx = threadIdx.x & 31, ty = threadIdx.x >> 5;   // ty 0..7
    #pragma unroll
    for (int i = 0; i < 4; i++)
        t[ty + 8 * i][tx] = W[(size_t)(k0 + ty + 8 * i) * 128 + n0 + tx];
    __syncthreads();
    #pragma unroll
    for (int i = 0; i < 4; i++) {
        float x = t[tx][ty + 8 * i];
        unsigned short h = f2bf(x);
        size_t off = (size_t)(n0 + ty + 8 * i) * DIM + k0 + tx;
        Th[off] = h;
        Tl[off] = f2bf(x - bf2f(h));
    }
}

// ---------------- MFMA GEMM: C = (Ah+Al) @ (Bh+Bl)^T, 3-pass split-bf16 ----
__global__ __launch_bounds__(256) void gemm_mfma(const unsigned short* __restrict__ Ah,
                                                 const unsigned short* __restrict__ Al,
                                                 const unsigned short* __restrict__ Bh,
                                                 const unsigned short* __restrict__ Bl,
                                                 unsigned short* __restrict__ Ch,
                                                 unsigned short* __restrict__ Cl) {
    __shared__ unsigned short As[128][32];   // 8 KB
    __shared__ unsigned short Bs[128][32];   // 8 KB
    const int bm = blockIdx.y * 128;
    const int bn = blockIdx.x * 128;
    const int tid = threadIdx.x;
    const int lane = tid & 63;
    const int wave = tid >> 6;
    const int wm = (wave >> 1) * 64, wn = (wave & 1) * 64;
    const int fr = lane & 15, fq = lane >> 4;
    const int sr = tid >> 2, sc = (tid & 3) * 8;
    f32x4 acc[4][4] = {};
    const unsigned short* Ap[3] = { Ah, Al, Ah };
    const unsigned short* Bp[3] = { Bh, Bh, Bl };
    for (int p = 0; p < 3; p++) {
        const unsigned short* Ag = Ap[p] + (size_t)(bm + sr) * DIM + sc;
        const unsigned short* Bg = Bp[p] + (size_t)(bn + sr) * DIM + sc;
        for (int kb = 0; kb < DIM; kb += 32) {
            __syncthreads();
            __builtin_amdgcn_global_load_lds(
                (const __attribute__((address_space(1))) void*)(Ag + kb),
                (__attribute__((address_space(3))) void*)(&As[sr][sc]), 16, 0, 0);
            __builtin_amdgcn_global_load_lds(
                (const __attribute__((address_space(1))) void*)(Ag + (size_t)64 * DIM + kb),
                (__attribute__((address_space(3))) void*)(&As[sr + 64][sc]), 16, 0, 0);
            __builtin_amdgcn_global_load_lds(
                (const __attribute__((address_space(1))) void*)(Bg + kb),
                (__attribute__((address_space(3))) void*)(&Bs[sr][sc]), 16, 0, 0);
            __builtin_amdgcn_global_load_lds(
                (const __attribute__((address_space(1))) void*)(Bg + (size_t)64 * DIM + kb),
                (__attribute__((address_space(3))) void*)(&Bs[sr + 64][sc]), 16, 0, 0);
            __syncthreads();
            short8 af[4], bfv[4];
            #pragma unroll
            for (int i = 0; i < 4; i++)
                af[i] = *(const short8*)&As[wm + i * 16 + fr][fq * 8];
            #pragma unroll
            for (int i = 0; i < 4; i++)
                bfv[i] = *(const short8*)&Bs[wn + i * 16 + fr][fq * 8];
            #pragma unroll
            for (int mi = 0; mi < 4; mi++)
                #pragma unroll
                for (int ni = 0; ni < 4; ni++)
                    acc[mi][ni] = __builtin_amdgcn_mfma_f32_16x16x32_bf16(
                        af[mi], bfv[ni], acc[mi][ni], 0, 0, 0);
        }
    }
    #pragma unroll
    for (int mi = 0; mi < 4; mi++)
        #pragma unroll
        for (int ni = 0; ni < 4; ni++)
            #pragma unroll
            for (int r = 0; r < 4; r++) {
                int row = bm + wm + mi * 16 + fq * 4 + r;
                int col = bn + wn + ni * 16 + fr;
                float v = acc[mi][ni][r];
                unsigned short h = f2bf(v);
                size_t off = (size_t)row * DIM + col;
                Ch[off] = h;
                Cl[off] = f2bf(v - bf2f(h));
            }
}

// ---------------- CSR by src ----------------
__global__ __launch_bounds__(256) void count_src(const int* __restrict__ src, int* counts) {
    int j = blockIdx.x * 256 + threadIdx.x;
    atomicAdd(&counts[src[j]], 1);
}

__global__ __launch_bounds__(256) void scan_offs(const int* __restrict__ counts,
                                                 int* __restrict__ offs, int* __restrict__ cur) {
    __shared__ int part[256];
    int t = threadIdx.x;
    int base = t * 32;
    int s = 0;
    for (int i = 0; i < 32; i++) s += counts[base + i];
    part[t] = s;
    __syncthreads();
    if (t == 0) {
        int run = 0;
        for (int i = 0; i < 256; i++) { int v = part[i]; part[i] = run; run += v; }
        offs[NN] = run;
    }
    __syncthreads();
    int run = part[t];
    for (int i = 0; i < 32; i++) {
        offs[base + i] = run;
        cur[base + i] = run;
        run += counts[base + i];
    }
}

__global__ __launch_bounds__(256) void scatter_src(const int* __restrict__ src,
                                                   int* cur, int* __restrict__ eid) {
    int j = blockIdx.x * 256 + threadIdx.x;
    int p = atomicAdd(&cur[src[j]], 1);
    eid[p] = j;
}

// ---------------- per-edge per-head dots + vals (CSR order, CANONICAL only) -
__global__ __launch_bounds__(256) void edge_dots_csr(const unsigned short* __restrict__ Ch,
                                                     const unsigned short* __restrict__ Cl,
                                                     const int* __restrict__ offs,
                                                     const int* __restrict__ eid,
                                                     const int* __restrict__ dst,
                                                     const float* __restrict__ trans,
                                                     float* __restrict__ e,
                                                     float* __restrict__ vals) {
    int n = blockIdx.x;
    int s0 = offs[n];
    int d = offs[n + 1] - s0;
    if (d <= 0) return;
    int wave = threadIdx.x >> 6, lane = threadIdx.x & 63;
    const uint4* ph = (const uint4*)(Ch + (size_t)n * DIM);
    const uint4* pl = (const uint4*)(Cl + (size_t)n * DIM);
    uint4 hv = ph[lane], lv = pl[lane];
    float a[8];
    a[0] = bf2f(hv.x & 0xffffu) + bf2f(lv.x & 0xffffu);
    a[1] = bf2f(hv.x >> 16)     + bf2f(lv.x >> 16);
    a[2] = bf2f(hv.y & 0xffffu) + bf2f(lv.y & 0xffffu);
    a[3] = bf2f(hv.y >> 16)     + bf2f(lv.y >> 16);
    a[4] = bf2f(hv.z & 0xffffu) + bf2f(lv.z & 0xffffu);
    a[5] = bf2f(hv.z >> 16)     + bf2f(lv.z >> 16);
    a[6] = bf2f(hv.w & 0xffffu) + bf2f(lv.w & 0xffffu);
    a[7] = bf2f(hv.w >> 16)     + bf2f(lv.w >> 16);
    for (int i = wave; i < d; i += 4) {
        int j = eid[s0 + i];
        if (j >= NE_HALF) continue;          // canonical copies only
        const uint4* qh = (const uint4*)(Ch + (size_t)dst[j] * DIM);
        const uint4* ql = (const uint4*)(Cl + (size_t)dst[j] * DIM);
        uint4 bh = qh[lane], bl = ql[lane];
        float p;
        p  = a[0] * (bf2f(bh.x & 0xffffu) + bf2f(bl.x & 0xffffu));
        p += a[1] * (bf2f(bh.x >> 16)     + bf2f(bl.x >> 16));
        p += a[2] * (bf2f(bh.y & 0xffffu) + bf2f(bl.y & 0xffffu));
        p += a[3] * (bf2f(bh.y >> 16)     + bf2f(bl.y >> 16));
        p += a[4] * (bf2f(bh.z & 0xffffu) + bf2f(bl.z & 0xffffu));
        p += a[5] * (bf2f(bh.z >> 16)     + bf2f(bl.z >> 16));
        p += a[6] * (bf2f(bh.w & 0xffffu) + bf2f(bl.w & 0xffffu));
        p += a[7] * (bf2f(bh.w >> 16)     + bf2f(bl.w >> 16));
        p += __shfl_xor(p, 1);
        p += __shfl_xor(p, 2);
        p += __shfl_xor(p, 4);           // per-head sums (head = lane>>3)
        if ((lane & 7) == 0) e[(size_t)j * NHEAD + (lane >> 3)] = p;
        p += __shfl_xor(p, 8);
        p += __shfl_xor(p, 16);
        p += __shfl_xor(p, 32);          // full 512-dim sum
        if (lane == 0) vals[j] = trans[j] * p;
    }
}

// ---------------- per-row coalesce + top-T threshold -> keep flags ----------
__global__ __launch_bounds__(128) void row_thresh(const int* __restrict__ offs,
                                                  const int* __restrict__ eid,
                                                  const int* __restrict__ dst,
                                                  const float* __restrict__ vals,
                                                  unsigned char* __restrict__ keep) {
    int r = blockIdx.x;
    int s0 = offs[r];
    int d = offs[r + 1] - s0;
    if (d > MAXDEG) d = MAXDEG;
    __shared__ int   sc[MAXDEG];
    __shared__ float sv[MAXDEG];
    __shared__ int   sj[MAXDEG];
    __shared__ float svc[MAXDEG];
    __shared__ unsigned char lead[MAXDEG];
    __shared__ float pos[MAXDEG];
    __shared__ float thr_s;
    for (int i = threadIdx.x; i < d; i += blockDim.x) {
        int j = eid[s0 + i];
        sj[i] = j; sc[i] = dst[j]; sv[i] = vals[j & CMASK];
    }
    __syncthreads();
    for (int i = threadIdx.x; i < d; i += blockDim.x) {
        int c = sc[i];
        float sum = 0.f;
        bool leader = true;
        for (int k = 0; k < d; k++) {
            if (sc[k] == c) {
                sum += sv[k];
                if (k < i) leader = false;
            }
        }
        svc[i] = sum;
        lead[i] = leader ? 1 : 0;
    }
    __syncthreads();
    if (threadIdx.x == 0) {
        int p = 0;
        for (int i = 0; i < d; i++)
            if (lead[i] && svc[i] > 0.f) pos[p++] = svc[i];
        float thr = 0.f;
        if (p >= TOPK) {
            for (int t = 0; t < TOPK; t++) {
                int mi = 0; float mv = -1e30f;
                for (int i = 0; i < p; i++)
                    if (pos[i] > mv) { mv = pos[i]; mi = i; }
                thr = mv;
                pos[mi] = -1e30f;
            }
        }
        thr_s = thr;
    }
    __syncthreads();
    float thr = thr_s;
    for (int i = threadIdx.x; i < d; i += blockDim.x)
        keep[sj[i]] = (svc[i] >= thr) ? 1 : 0;
}

// ---------------- edge softmax by dst + aggregation + ELU (bf16 reads) -----
__global__ __launch_bounds__(256) void aggregate(const int* __restrict__ offs,
                                                 const int* __restrict__ eid,
                                                 const int* __restrict__ dst,
                                                 const float* __restrict__ e,
                                                 const unsigned char* __restrict__ keep,
                                                 const unsigned short* __restrict__ fb,
                                                 unsigned short* __restrict__ zb) {
    int n = blockIdx.x;
    int s0 = offs[n];
    int d = offs[n + 1] - s0;
    if (d > MAXDEG) d = MAXDEG;
    __shared__ float sa[MAXDEG][NHEAD];  // 16 KB
    __shared__ int ssrc[MAXDEG];
    __shared__ float sm[NHEAD], ss[NHEAD];
    for (int i = threadIdx.x; i < d; i += blockDim.x) {
        int j = eid[s0 + i];
        ssrc[i] = dst[j];
        int kp = keep[j];
        const float* ep = e + (size_t)(j & CMASK) * NHEAD;
        #pragma unroll
        for (int h = 0; h < NHEAD; h++) sa[i][h] = kp ? ep[h] : NEGV;
    }
    __syncthreads();
    if (threadIdx.x < NHEAD) {
        int h = threadIdx.x;
        float m = -INFINITY;
        for (int i = 0; i < d; i++) m = fmaxf(m, sa[i][h]);
        float s = 0.f;
        for (int i = 0; i < d; i++) s += expf(sa[i][h] - m);
        sm[h] = m; ss[h] = s;
    }
    __syncthreads();
    for (int i = threadIdx.x; i < d * NHEAD; i += blockDim.x) {
        int ii = i >> 3, h = i & 7;
        sa[ii][h] = expf(sa[ii][h] - sm[h]) / ss[h];
    }
    __syncthreads();
    int c0 = threadIdx.x * 2;
    int h = c0 >> 6;
    float acc0 = 0.f, acc1 = 0.f;
    for (int i = 0; i < d; i++) {
        const unsigned short* row = fb + (size_t)ssrc[i] * DIM;
        unsigned int v = *(const unsigned int*)(row + c0);
        float a = sa[i][h];
        acc0 += a * bf2f(v & 0xffffu);
        acc1 += a * bf2f(v >> 16);
    }
    acc0 = acc0 > 0.f ? acc0 : expf(acc0) - 1.f;   // elu
    acc1 = acc1 > 0.f ? acc1 : expf(acc1) - 1.f;
    zb[(size_t)n * DIM + c0] = f2bf(acc0);
    zb[(size_t)n * DIM + c0 + 1] = f2bf(acc1);
}

// ---------------- semantic attention scores (MFMA, fused tanh epilogue) -----
// wsum[m] += sum_n tanh(Z_m[n] @ (W1h+W1l) + b1) @ w2 ; Z bf16, W1 split bf16
// block: 64 rows x 128 cols; wave w -> rows [w*16, w*16+16).
__global__ __launch_bounds__(256) void sem_scores3(const unsigned short* __restrict__ z0,
                                                   const unsigned short* __restrict__ z1,
                                                   const unsigned short* __restrict__ W1hT,
                                                   const unsigned short* __restrict__ W1lT,
                                                   const float* __restrict__ b1,
                                                   const float* __restrict__ w2,
                                                   float* wsum) {
    const unsigned short* Z = blockIdx.y ? z1 : z0;
    const int bm = blockIdx.x * 64;
    const int tid = threadIdx.x;
    const int lane = tid & 63, wave = tid >> 6;
    const int fr = lane & 15, fq = lane >> 4;
    __shared__ unsigned short Zs[64][32];     // 4 KB
    __shared__ unsigned short Wh[128][32];    // 8 KB
    __shared__ unsigned short Wl[128][32];    // 8 KB
    const int sr = tid >> 2, sc = (tid & 3) * 8;
    f32x4 acc[8] = {};
    const unsigned short* Zg  = Z    + (size_t)(bm + sr) * DIM + sc;
    const unsigned short* Whg = W1hT + (size_t)sr * DIM + sc;
    const unsigned short* Wlg = W1lT + (size_t)sr * DIM + sc;
    for (int kb = 0; kb < DIM; kb += 32) {
        __syncthreads();
        __builtin_amdgcn_global_load_lds(
            (const __attribute__((address_space(1))) void*)(Zg + kb),
            (__attribute__((address_space(3))) void*)(&Zs[sr][sc]), 16, 0, 0);
        __builtin_amdgcn_global_load_lds(
            (const __attribute__((address_space(1))) void*)(Whg + kb),
            (__attribute__((address_space(3))) void*)(&Wh[sr][sc]), 16, 0, 0);
        __builtin_amdgcn_global_load_lds(
            (const __attribute__((address_space(1))) void*)(Whg + (size_t)64 * DIM + kb),
            (__attribute__((address_space(3))) void*)(&Wh[sr + 64][sc]), 16, 0, 0);
        __builtin_amdgcn_global_load_lds(
            (const __attribute__((address_space(1))) void*)(Wlg + kb),
            (__attribute__((address_space(3))) void*)(&Wl[sr][sc]), 16, 0, 0);
        __builtin_amdgcn_global_load_lds(
            (const __attribute__((address_space(1))) void*)(Wlg + (size_t)64 * DIM + kb),
            (__attribute__((address_space(3))) void*)(&Wl[sr + 64][sc]), 16, 0, 0);
        __syncthreads();
        short8 af = *(const short8*)&Zs[wave * 16 + fr][fq * 8];
        #pragma unroll
        for (int ni = 0; ni < 8; ni++) {
            short8 bh = *(const short8*)&Wh[ni * 16 + fr][fq * 8];
            acc[ni] = __builtin_amdgcn_mfma_f32_16x16x32_bf16(af, bh, acc[ni], 0, 0, 0);
        }
        #pragma unroll
        for (int ni = 0; ni < 8; ni++) {
            short8 bl = *(const short8*)&Wl[ni * 16 + fr][fq * 8];
            acc[ni] = __builtin_amdgcn_mfma_f32_16x16x32_bf16(af, bl, acc[ni], 0, 0, 0);
        }
    }
    float local = 0.f;
    #pragma unroll
    for (int ni = 0; ni < 8; ni++) {
        int col = ni * 16 + fr;
        float bb = b1[col], ww = w2[col];
        #pragma unroll
        for (int r = 0; r < 4; r++)
            local += tanhf(acc[ni][r] + bb) * ww;
    }
    __shared__ float red[256];
    red[tid] = local;
    __syncthreads();
    for (int s = 128; s > 0; s >>= 1) {
        if (tid < s) red[tid] += red[tid + s];
        __syncthreads();
    }
    if (tid == 0) atomicAdd(&wsum[blockIdx.y], red[0]);
}

// ---------------- final: beta-weighted combine + linear ----------------
__global__ __launch_bounds__(256) void final_out(const unsigned short* __restrict__ z0,
                                                 const unsigned short* __restrict__ z1,
                                                 const float* __restrict__ wsum,
                                                 const float* __restrict__ lin_w,
                                                 const float* __restrict__ lin_b,
                                                 float* __restrict__ out) {
    int idx = blockIdx.x * 256 + threadIdx.x;   // 24576 threads
    int n = idx / 3, o = idx - n * 3;
    float w0 = wsum[0] * (1.0f / NN), w1v = wsum[1] * (1.0f / NN);
    float mx = fmaxf(w0, w1v);
    float e0 = expf(w0 - mx), e1 = expf(w1v - mx);
    float beta0 = e0 / (e0 + e1), beta1 = e1 / (e0 + e1);
    const unsigned short* p0 = z0 + (size_t)n * DIM;
    const unsigned short* p1 = z1 + (size_t)n * DIM;
    float acc = 0.f;
    for (int dd = 0; dd < DIM; dd++)
        acc += (beta0 * bf2f(p0[dd]) + beta1 * bf2f(p1[dd])) * lin_w[dd * 3 + o];
    out[idx] = acc + lin_b[o];
}

// ---------------- launch ----------------
extern "C" void kernel_launch(void* const* d_in, const int* in_sizes, int n_in,
                              void* d_out, int out_size, void* d_ws, size_t ws_size,
                              hipStream_t stream) {
    const float* feat = (const float*)d_in[0];
    const int*   srcp[2]   = { (const int*)d_in[1], (const int*)d_in[4] };
    const int*   dstp[2]   = { (const int*)d_in[2], (const int*)d_in[5] };
    const float* transp[2] = { (const float*)d_in[3], (const float*)d_in[6] };
    const float* fcw[2]    = { (const float*)d_in[7], (const float*)d_in[8] };
    const float* sem_w1 = (const float*)d_in[9];
    const float* sem_b1 = (const float*)d_in[10];
    const float* sem_w2 = (const float*)d_in[11];
    const float* lin_w  = (const float*)d_in[12];
    const float* lin_b  = (const float*)d_in[13];
    float* out = (float*)d_out;

    char* ws = (char*)d_ws;
    const size_t MB = 1 << 20;
    const size_t KB = 1 << 10;
    if (ws_size < 56 * MB) return;
    unsigned short* Ch    = (unsigned short*)(ws);               //  8 MB
    unsigned short* Cl    = (unsigned short*)(ws + 8 * MB);      //  8 MB
    unsigned short* z0    = (unsigned short*)(ws + 16 * MB);     //  8 MB
    unsigned short* z1    = (unsigned short*)(ws + 24 * MB);     //  8 MB
    unsigned short* fH    = (unsigned short*)(ws + 32 * MB);     //  8 MB
    unsigned short* fL    = (unsigned short*)(ws + 40 * MB);     //  8 MB
    float*          e     = (float*)(ws + 48 * MB);              //  4 MB (NE_HALF*8)
    float*          vals  = (float*)(ws + 52 * MB);              // 512 KB
    int*            eid   = (int*)  (ws + 52 * MB + 512 * KB);   //  1 MB
    unsigned short* BhT   = (unsigned short*)(ws + 53 * MB + 512 * KB);  // 512 KB
    unsigned short* BlT   = (unsigned short*)(ws + 54 * MB);             // 512 KB
    unsigned short* W1hT  = (unsigned short*)(ws + 54 * MB + 512 * KB);  // 128 KB
    unsigned short* W1lT  = (unsigned short*)(ws + 54 * MB + 640 * KB);  // 128 KB
    unsigned char*  keep  = (unsigned char*)(ws + 54 * MB + 768 * KB);   // 256 KB
    int*            counts= (int*)  (ws + 55 * MB);              // 32 KB
    int*            offs  = (int*)  (ws + 55 * MB + 32 * KB);    // 36 KB
    int*            cur   = (int*)  (ws + 55 * MB + 96 * KB);    // 32 KB
    float*          wsum  = (float*)(ws + 55 * MB + 160 * KB);

    split_feat<<<(NN * DIM / 4) / 256, 256, 0, stream>>>(feat, fH, fL);
    split_w1t<<<dim3(4, 16), 256, 0, stream>>>(sem_w1, W1hT, W1lT);
    for (int c = 0; c < 2; c++) {
        unsigned short* z = c ? z1 : z0;
        hipMemsetAsync(counts, 0, NN * sizeof(int), stream);
        count_src<<<NE / 256, 256, 0, stream>>>(srcp[c], counts);
        scan_offs<<<1, 256, 0, stream>>>(counts, offs, cur);
        scatter_src<<<NE / 256, 256, 0, stream>>>(srcp[c], cur, eid);
        split_w<<<dim3(16, 16), 256, 0, stream>>>(fcw[c], BhT, BlT);
        gemm_mfma<<<dim3(4, 64), 256, 0, stream>>>(fH, fL, BhT, BlT, Ch, Cl);
        edge_dots_csr<<<NN, 256, 0, stream>>>(Ch, Cl, offs, eid, dstp[c], transp[c], e, vals);
        row_thresh<<<NN, 128, 0, stream>>>(offs, eid, dstp[c], vals, keep);
        aggregate<<<NN, 256, 0, stream>>>(offs, eid, dstp[c], e, keep, Ch, z);
    }
    hipMemsetAsync(wsum, 0, 2 * sizeof(float), stream);
    sem_scores3<<<dim3(NN / 64, 2), 256, 0, stream>>>(z0, z1, W1hT, W1lT, sem_b1, sem_w2, wsum);
    final_out<<<(NN * 3) / 256, 256, 0, stream>>>(z0, z1, wsum, lin_w, lin_b, out);
}

// Round 8
// 569.655 us; speedup vs baseline: 1.2945x; 1.0011x over previous
//
#include <hip/hip_runtime.h>
#include <math.h>

#define NN      8192
#define DIM     512      // IN_DIM == H*HID
#define NHEAD   8
#define HID     64
#define NE      262144
#define NE_HALF 131072
#define CMASK   (NE_HALF - 1)      // canonical edge id = j & CMASK (graph symmetric)
#define TOPK    10
#define NEGV    -9e15f
#define MAXDEG  512

typedef __attribute__((ext_vector_type(8))) short short8;
typedef __attribute__((ext_vector_type(4))) float f32x4;

__device__ __forceinline__ float bf2f(unsigned int h) {
    return __uint_as_float(h << 16);
}
__device__ __forceinline__ unsigned short f2bf(float x) {
    unsigned int u = __float_as_uint(x);
    unsigned int r = (u + 0x7fff + ((u >> 16) & 1)) >> 16;   // RNE
    return (unsigned short)r;
}

// ---------------- split fp32 -> (hi, lo) bf16 ----------------
__global__ __launch_bounds__(256) void split_feat(const float* __restrict__ X,
                                                  unsigned short* __restrict__ H,
                                                  unsigned short* __restrict__ L) {
    int i = blockIdx.x * 256 + threadIdx.x;           // over float4s
    float4 v = ((const float4*)X)[i];
    unsigned short h0 = f2bf(v.x), h1 = f2bf(v.y), h2 = f2bf(v.z), h3 = f2bf(v.w);
    ushort4 hv; hv.x = h0; hv.y = h1; hv.z = h2; hv.w = h3;
    ushort4 lv;
    lv.x = f2bf(v.x - bf2f(h0));
    lv.y = f2bf(v.y - bf2f(h1));
    lv.z = f2bf(v.z - bf2f(h2));
    lv.w = f2bf(v.w - bf2f(h3));
    ((ushort4*)H)[i] = hv;
    ((ushort4*)L)[i] = lv;
}

// W[512][512] fp32 -> transposed split Th/Tl [n][k] bf16
__global__ __launch_bounds__(256) void split_w(const float* __restrict__ W,
                                               unsigned short* __restrict__ Th,
                                               unsigned short* __restrict__ Tl) {
    __shared__ float t[32][33];
    int k0 = blockIdx.y * 32, n0 = blockIdx.x * 32;
    int tx = threadIdx.x & 31, ty = threadIdx.x >> 5;   // ty 0..7
    #pragma unroll
    for (int i = 0; i < 4; i++)
        t[ty + 8 * i][tx] = W[(size_t)(k0 + ty + 8 * i) * DIM + n0 + tx];
    __syncthreads();
    #pragma unroll
    for (int i = 0; i < 4; i++) {
        float x = t[tx][ty + 8 * i];
        unsigned short h = f2bf(x);
        size_t off = (size_t)(n0 + ty + 8 * i) * DIM + k0 + tx;
        Th[off] = h;
        Tl[off] = f2bf(x - bf2f(h));
    }
}

// sem_w1[512][128] fp32 -> transposed split [128 cols][512 k] bf16 hi/lo
__global__ __launch_bounds__(256) void split_w1t(const float* __restrict__ W,
                                                 unsigned short* __restrict__ Th,
                                                 unsigned short* __restrict__ Tl) {
    __shared__ float t[32][33];
    int n0 = blockIdx.x * 32;      // cols (0..127)
    int k0 = blockIdx.y * 32;      // k    (0..511)
    int tx = threadIdx.x & 31, ty = threadIdx.x >> 5;   // ty 0..7
    #pragma unroll
    for (int i = 0; i < 4; i++)
        t[ty + 8 * i][tx] = W[(size_t)(k0 + ty + 8 * i) * 128 + n0 + tx];
    __syncthreads();
    #pragma unroll
    for (int i = 0; i < 4; i++) {
        float x = t[tx][ty + 8 * i];
        unsigned short h = f2bf(x);
        size_t off = (size_t)(n0 + ty + 8 * i) * DIM + k0 + tx;
        Th[off] = h;
        Tl[off] = f2bf(x - bf2f(h));
    }
}

// ---------------- MFMA GEMM, merged split passes in K-loop ----------------
// C = (Ah+Al)@(Bh+Bl)^T ~= Ah·Bh + Al·Bh + Ah·Bl, accumulated per K-step.
// Tile 128x64, grid (8,64) = 512 blocks (2/CU). LDS 24 KB.
__global__ __launch_bounds__(256) void gemm_mfma(const unsigned short* __restrict__ Ah,
                                                 const unsigned short* __restrict__ Al,
                                                 const unsigned short* __restrict__ Bh,
                                                 const unsigned short* __restrict__ Bl,
                                                 unsigned short* __restrict__ Ch,
                                                 unsigned short* __restrict__ Cl) {
    __shared__ unsigned short Ash[128][32];   // 8 KB
    __shared__ unsigned short Asl[128][32];   // 8 KB
    __shared__ unsigned short Bsh[64][32];    // 4 KB
    __shared__ unsigned short Bsl[64][32];    // 4 KB
    const int bm = blockIdx.y * 128;
    const int bn = blockIdx.x * 64;
    const int tid = threadIdx.x;
    const int lane = tid & 63;
    const int wave = tid >> 6;
    const int wm = (wave >> 1) * 64, wn = (wave & 1) * 32;
    const int fr = lane & 15, fq = lane >> 4;
    const int sr = tid >> 2, sc = (tid & 3) * 8;
    f32x4 acc[4][2] = {};
    const unsigned short* Ahg = Ah + (size_t)(bm + sr) * DIM + sc;
    const unsigned short* Alg = Al + (size_t)(bm + sr) * DIM + sc;
    const unsigned short* Bhg = Bh + (size_t)(bn + sr) * DIM + sc;   // sr<64 rows used
    const unsigned short* Blg = Bl + (size_t)(bn + sr) * DIM + sc;
    for (int kb = 0; kb < DIM; kb += 32) {
        __syncthreads();
        __builtin_amdgcn_global_load_lds(
            (const __attribute__((address_space(1))) void*)(Ahg + kb),
            (__attribute__((address_space(3))) void*)(&Ash[sr][sc]), 16, 0, 0);
        __builtin_amdgcn_global_load_lds(
            (const __attribute__((address_space(1))) void*)(Ahg + (size_t)64 * DIM + kb),
            (__attribute__((address_space(3))) void*)(&Ash[sr + 64][sc]), 16, 0, 0);
        __builtin_amdgcn_global_load_lds(
            (const __attribute__((address_space(1))) void*)(Alg + kb),
            (__attribute__((address_space(3))) void*)(&Asl[sr][sc]), 16, 0, 0);
        __builtin_amdgcn_global_load_lds(
            (const __attribute__((address_space(1))) void*)(Alg + (size_t)64 * DIM + kb),
            (__attribute__((address_space(3))) void*)(&Asl[sr + 64][sc]), 16, 0, 0);
        if (sr < 64) {
            __builtin_amdgcn_global_load_lds(
                (const __attribute__((address_space(1))) void*)(Bhg + kb),
                (__attribute__((address_space(3))) void*)(&Bsh[sr][sc]), 16, 0, 0);
            __builtin_amdgcn_global_load_lds(
                (const __attribute__((address_space(1))) void*)(Blg + kb),
                (__attribute__((address_space(3))) void*)(&Bsl[sr][sc]), 16, 0, 0);
        }
        __syncthreads();
        short8 ah[4], al[4], bh[2], bl[2];
        #pragma unroll
        for (int i = 0; i < 4; i++) {
            ah[i] = *(const short8*)&Ash[wm + i * 16 + fr][fq * 8];
            al[i] = *(const short8*)&Asl[wm + i * 16 + fr][fq * 8];
        }
        #pragma unroll
        for (int i = 0; i < 2; i++) {
            bh[i] = *(const short8*)&Bsh[wn + i * 16 + fr][fq * 8];
            bl[i] = *(const short8*)&Bsl[wn + i * 16 + fr][fq * 8];
        }
        #pragma unroll
        for (int mi = 0; mi < 4; mi++)
            #pragma unroll
            for (int ni = 0; ni < 2; ni++) {
                acc[mi][ni] = __builtin_amdgcn_mfma_f32_16x16x32_bf16(ah[mi], bh[ni], acc[mi][ni], 0, 0, 0);
                acc[mi][ni] = __builtin_amdgcn_mfma_f32_16x16x32_bf16(al[mi], bh[ni], acc[mi][ni], 0, 0, 0);
                acc[mi][ni] = __builtin_amdgcn_mfma_f32_16x16x32_bf16(ah[mi], bl[ni], acc[mi][ni], 0, 0, 0);
            }
    }
    #pragma unroll
    for (int mi = 0; mi < 4; mi++)
        #pragma unroll
        for (int ni = 0; ni < 2; ni++)
            #pragma unroll
            for (int r = 0; r < 4; r++) {
                int row = bm + wm + mi * 16 + fq * 4 + r;
                int col = bn + wn + ni * 16 + fr;
                float v = acc[mi][ni][r];
                unsigned short h = f2bf(v);
                size_t off = (size_t)row * DIM + col;
                Ch[off] = h;
                Cl[off] = f2bf(v - bf2f(h));
            }
}

// ---------------- CSR by src (full + canonical-only) ----------------
__global__ __launch_bounds__(256) void count_src(const int* __restrict__ src, int* counts) {
    int j = blockIdx.x * 256 + threadIdx.x;
    atomicAdd(&counts[src[j]], 1);
}

__global__ __launch_bounds__(256) void scan_offs(const int* __restrict__ counts,
                                                 int* __restrict__ offs, int* __restrict__ cur) {
    __shared__ int part[256];
    int t = threadIdx.x;
    int base = t * 32;
    int s = 0;
    for (int i = 0; i < 32; i++) s += counts[base + i];
    part[t] = s;
    __syncthreads();
    if (t == 0) {
        int run = 0;
        for (int i = 0; i < 256; i++) { int v = part[i]; part[i] = run; run += v; }
        offs[NN] = run;
    }
    __syncthreads();
    int run = part[t];
    for (int i = 0; i < 32; i++) {
        offs[base + i] = run;
        cur[base + i] = run;
        run += counts[base + i];
    }
}

__global__ __launch_bounds__(256) void scatter_src(const int* __restrict__ src,
                                                   int* cur, int* __restrict__ eid) {
    int j = blockIdx.x * 256 + threadIdx.x;
    int p = atomicAdd(&cur[src[j]], 1);
    eid[p] = j;
}

// ---------------- per-edge dots (compact canonical CSR, unroll-2 MLP) ------
// e[j][h], vals[j] once per undirected edge; consumers use j & CMASK.
__global__ __launch_bounds__(256) void edge_dots_csr(const unsigned short* __restrict__ Ch,
                                                     const unsigned short* __restrict__ Cl,
                                                     const int* __restrict__ coffs,
                                                     const int* __restrict__ ceid,
                                                     const int* __restrict__ dst,
                                                     const float* __restrict__ trans,
                                                     float* __restrict__ e,
                                                     float* __restrict__ vals) {
    int n = blockIdx.x;
    int s0 = coffs[n];
    int d = coffs[n + 1] - s0;
    if (d <= 0) return;
    int wave = threadIdx.x >> 6, lane = threadIdx.x & 63;
    const uint4* ph = (const uint4*)(Ch + (size_t)n * DIM);
    const uint4* pl = (const uint4*)(Cl + (size_t)n * DIM);
    uint4 hv = ph[lane], lv = pl[lane];
    float a[8];
    a[0] = bf2f(hv.x & 0xffffu) + bf2f(lv.x & 0xffffu);
    a[1] = bf2f(hv.x >> 16)     + bf2f(lv.x >> 16);
    a[2] = bf2f(hv.y & 0xffffu) + bf2f(lv.y & 0xffffu);
    a[3] = bf2f(hv.y >> 16)     + bf2f(lv.y >> 16);
    a[4] = bf2f(hv.z & 0xffffu) + bf2f(lv.z & 0xffffu);
    a[5] = bf2f(hv.z >> 16)     + bf2f(lv.z >> 16);
    a[6] = bf2f(hv.w & 0xffffu) + bf2f(lv.w & 0xffffu);
    a[7] = bf2f(hv.w >> 16)     + bf2f(lv.w >> 16);
    for (int i = wave; i < d; i += 8) {
        int j0 = ceid[s0 + i];
        int i1 = i + 4;
        bool has1 = i1 < d;
        int j1 = has1 ? ceid[s0 + i1] : j0;
        const uint4* qh0 = (const uint4*)(Ch + (size_t)dst[j0] * DIM);
        const uint4* ql0 = (const uint4*)(Cl + (size_t)dst[j0] * DIM);
        const uint4* qh1 = (const uint4*)(Ch + (size_t)dst[j1] * DIM);
        const uint4* ql1 = (const uint4*)(Cl + (size_t)dst[j1] * DIM);
        uint4 bh0 = qh0[lane], bl0 = ql0[lane];
        uint4 bh1 = qh1[lane], bl1 = ql1[lane];
        float p0, p1;
        p0  = a[0] * (bf2f(bh0.x & 0xffffu) + bf2f(bl0.x & 0xffffu));
        p0 += a[1] * (bf2f(bh0.x >> 16)     + bf2f(bl0.x >> 16));
        p0 += a[2] * (bf2f(bh0.y & 0xffffu) + bf2f(bl0.y & 0xffffu));
        p0 += a[3] * (bf2f(bh0.y >> 16)     + bf2f(bl0.y >> 16));
        p0 += a[4] * (bf2f(bh0.z & 0xffffu) + bf2f(bl0.z & 0xffffu));
        p0 += a[5] * (bf2f(bh0.z >> 16)     + bf2f(bl0.z >> 16));
        p0 += a[6] * (bf2f(bh0.w & 0xffffu) + bf2f(bl0.w & 0xffffu));
        p0 += a[7] * (bf2f(bh0.w >> 16)     + bf2f(bl0.w >> 16));
        p1  = a[0] * (bf2f(bh1.x & 0xffffu) + bf2f(bl1.x & 0xffffu));
        p1 += a[1] * (bf2f(bh1.x >> 16)     + bf2f(bl1.x >> 16));
        p1 += a[2] * (bf2f(bh1.y & 0xffffu) + bf2f(bl1.y & 0xffffu));
        p1 += a[3] * (bf2f(bh1.y >> 16)     + bf2f(bl1.y >> 16));
        p1 += a[4] * (bf2f(bh1.z & 0xffffu) + bf2f(bl1.z & 0xffffu));
        p1 += a[5] * (bf2f(bh1.z >> 16)     + bf2f(bl1.z >> 16));
        p1 += a[6] * (bf2f(bh1.w & 0xffffu) + bf2f(bl1.w & 0xffffu));
        p1 += a[7] * (bf2f(bh1.w >> 16)     + bf2f(bl1.w >> 16));
        p0 += __shfl_xor(p0, 1);
        p0 += __shfl_xor(p0, 2);
        p0 += __shfl_xor(p0, 4);
        p1 += __shfl_xor(p1, 1);
        p1 += __shfl_xor(p1, 2);
        p1 += __shfl_xor(p1, 4);
        if ((lane & 7) == 0) e[(size_t)j0 * NHEAD + (lane >> 3)] = p0;
        if (has1 && (lane & 7) == 0) e[(size_t)j1 * NHEAD + (lane >> 3)] = p1;
        p0 += __shfl_xor(p0, 8);
        p0 += __shfl_xor(p0, 16);
        p0 += __shfl_xor(p0, 32);
        p1 += __shfl_xor(p1, 8);
        p1 += __shfl_xor(p1, 16);
        p1 += __shfl_xor(p1, 32);
        if (lane == 0) {
            vals[j0] = trans[j0] * p0;
            if (has1) vals[j1] = trans[j1] * p1;
        }
    }
}

// ---------------- per-row coalesce + top-T threshold -> keep flags ----------
__global__ __launch_bounds__(128) void row_thresh(const int* __restrict__ offs,
                                                  const int* __restrict__ eid,
                                                  const int* __restrict__ dst,
                                                  const float* __restrict__ vals,
                                                  unsigned char* __restrict__ keep) {
    int r = blockIdx.x;
    int s0 = offs[r];
    int d = offs[r + 1] - s0;
    if (d > MAXDEG) d = MAXDEG;
    __shared__ int   sc[MAXDEG];
    __shared__ float sv[MAXDEG];
    __shared__ int   sj[MAXDEG];
    __shared__ float svc[MAXDEG];
    __shared__ unsigned char lead[MAXDEG];
    __shared__ float pos[MAXDEG];
    __shared__ float thr_s;
    for (int i = threadIdx.x; i < d; i += blockDim.x) {
        int j = eid[s0 + i];
        sj[i] = j; sc[i] = dst[j]; sv[i] = vals[j & CMASK];
    }
    __syncthreads();
    for (int i = threadIdx.x; i < d; i += blockDim.x) {
        int c = sc[i];
        float sum = 0.f;
        bool leader = true;
        for (int k = 0; k < d; k++) {
            if (sc[k] == c) {
                sum += sv[k];
                if (k < i) leader = false;
            }
        }
        svc[i] = sum;
        lead[i] = leader ? 1 : 0;
    }
    __syncthreads();
    if (threadIdx.x == 0) {
        int p = 0;
        for (int i = 0; i < d; i++)
            if (lead[i] && svc[i] > 0.f) pos[p++] = svc[i];
        float thr = 0.f;
        if (p >= TOPK) {
            for (int t = 0; t < TOPK; t++) {
                int mi = 0; float mv = -1e30f;
                for (int i = 0; i < p; i++)
                    if (pos[i] > mv) { mv = pos[i]; mi = i; }
                thr = mv;
                pos[mi] = -1e30f;
            }
        }
        thr_s = thr;
    }
    __syncthreads();
    float thr = thr_s;
    for (int i = threadIdx.x; i < d; i += blockDim.x)
        keep[sj[i]] = (svc[i] >= thr) ? 1 : 0;
}

// ---------------- edge softmax by dst + aggregation + ELU (bf16 reads) -----
__global__ __launch_bounds__(256) void aggregate(const int* __restrict__ offs,
                                                 const int* __restrict__ eid,
                                                 const int* __restrict__ dst,
                                                 const float* __restrict__ e,
                                                 const unsigned char* __restrict__ keep,
                                                 const unsigned short* __restrict__ fb,
                                                 unsigned short* __restrict__ zb) {
    int n = blockIdx.x;
    int s0 = offs[n];
    int d = offs[n + 1] - s0;
    if (d > MAXDEG) d = MAXDEG;
    __shared__ float sa[MAXDEG][NHEAD];  // 16 KB
    __shared__ int ssrc[MAXDEG];
    __shared__ float sm[NHEAD], ss[NHEAD];
    for (int i = threadIdx.x; i < d; i += blockDim.x) {
        int j = eid[s0 + i];
        ssrc[i] = dst[j];
        int kp = keep[j];
        const float* ep = e + (size_t)(j & CMASK) * NHEAD;
        #pragma unroll
        for (int h = 0; h < NHEAD; h++) sa[i][h] = kp ? ep[h] : NEGV;
    }
    __syncthreads();
    if (threadIdx.x < NHEAD) {
        int h = threadIdx.x;
        float m = -INFINITY;
        for (int i = 0; i < d; i++) m = fmaxf(m, sa[i][h]);
        float s = 0.f;
        for (int i = 0; i < d; i++) s += expf(sa[i][h] - m);
        sm[h] = m; ss[h] = s;
    }
    __syncthreads();
    for (int i = threadIdx.x; i < d * NHEAD; i += blockDim.x) {
        int ii = i >> 3, h = i & 7;
        sa[ii][h] = expf(sa[ii][h] - sm[h]) / ss[h];
    }
    __syncthreads();
    int c0 = threadIdx.x * 2;
    int h = c0 >> 6;
    float acc0 = 0.f, acc1 = 0.f;
    for (int i = 0; i < d; i++) {
        const unsigned short* row = fb + (size_t)ssrc[i] * DIM;
        unsigned int v = *(const unsigned int*)(row + c0);
        float a = sa[i][h];
        acc0 += a * bf2f(v & 0xffffu);
        acc1 += a * bf2f(v >> 16);
    }
    acc0 = acc0 > 0.f ? acc0 : expf(acc0) - 1.f;   // elu
    acc1 = acc1 > 0.f ? acc1 : expf(acc1) - 1.f;
    zb[(size_t)n * DIM + c0] = f2bf(acc0);
    zb[(size_t)n * DIM + c0 + 1] = f2bf(acc1);
}

// ---------------- semantic attention scores (MFMA, fused tanh epilogue) -----
__global__ __launch_bounds__(256) void sem_scores3(const unsigned short* __restrict__ z0,
                                                   const unsigned short* __restrict__ z1,
                                                   const unsigned short* __restrict__ W1hT,
                                                   const unsigned short* __restrict__ W1lT,
                                                   const float* __restrict__ b1,
                                                   const float* __restrict__ w2,
                                                   float* wsum) {
    const unsigned short* Z = blockIdx.y ? z1 : z0;
    const int bm = blockIdx.x * 64;
    const int tid = threadIdx.x;
    const int lane = tid & 63, wave = tid >> 6;
    const int fr = lane & 15, fq = lane >> 4;
    __shared__ unsigned short Zs[64][32];     // 4 KB
    __shared__ unsigned short Wh[128][32];    // 8 KB
    __shared__ unsigned short Wl[128][32];    // 8 KB
    const int sr = tid >> 2, sc = (tid & 3) * 8;
    f32x4 acc[8] = {};
    const unsigned short* Zg  = Z    + (size_t)(bm + sr) * DIM + sc;
    const unsigned short* Whg = W1hT + (size_t)sr * DIM + sc;
    const unsigned short* Wlg = W1lT + (size_t)sr * DIM + sc;
    for (int kb = 0; kb < DIM; kb += 32) {
        __syncthreads();
        __builtin_amdgcn_global_load_lds(
            (const __attribute__((address_space(1))) void*)(Zg + kb),
            (__attribute__((address_space(3))) void*)(&Zs[sr][sc]), 16, 0, 0);
        __builtin_amdgcn_global_load_lds(
            (const __attribute__((address_space(1))) void*)(Whg + kb),
            (__attribute__((address_space(3))) void*)(&Wh[sr][sc]), 16, 0, 0);
        __builtin_amdgcn_global_load_lds(
            (const __attribute__((address_space(1))) void*)(Whg + (size_t)64 * DIM + kb),
            (__attribute__((address_space(3))) void*)(&Wh[sr + 64][sc]), 16, 0, 0);
        __builtin_amdgcn_global_load_lds(
            (const __attribute__((address_space(1))) void*)(Wlg + kb),
            (__attribute__((address_space(3))) void*)(&Wl[sr][sc]), 16, 0, 0);
        __builtin_amdgcn_global_load_lds(
            (const __attribute__((address_space(1))) void*)(Wlg + (size_t)64 * DIM + kb),
            (__attribute__((address_space(3))) void*)(&Wl[sr + 64][sc]), 16, 0, 0);
        __syncthreads();
        short8 af = *(const short8*)&Zs[wave * 16 + fr][fq * 8];
        #pragma unroll
        for (int ni = 0; ni < 8; ni++) {
            short8 bh = *(const short8*)&Wh[ni * 16 + fr][fq * 8];
            acc[ni] = __builtin_amdgcn_mfma_f32_16x16x32_bf16(af, bh, acc[ni], 0, 0, 0);
        }
        #pragma unroll
        for (int ni = 0; ni < 8; ni++) {
            short8 bl = *(const short8*)&Wl[ni * 16 + fr][fq * 8];
            acc[ni] = __builtin_amdgcn_mfma_f32_16x16x32_bf16(af, bl, acc[ni], 0, 0, 0);
        }
    }
    float local = 0.f;
    #pragma unroll
    for (int ni = 0; ni < 8; ni++) {
        int col = ni * 16 + fr;
        float bb = b1[col], ww = w2[col];
        #pragma unroll
        for (int r = 0; r < 4; r++)
            local += tanhf(acc[ni][r] + bb) * ww;
    }
    __shared__ float red[256];
    red[tid] = local;
    __syncthreads();
    for (int s = 128; s > 0; s >>= 1) {
        if (tid < s) red[tid] += red[tid + s];
        __syncthreads();
    }
    if (tid == 0) atomicAdd(&wsum[blockIdx.y], red[0]);
}

// ---------------- final: beta-weighted combine + linear ----------------
__global__ __launch_bounds__(256) void final_out(const unsigned short* __restrict__ z0,
                                                 const unsigned short* __restrict__ z1,
                                                 const float* __restrict__ wsum,
                                                 const float* __restrict__ lin_w,
                                                 const float* __restrict__ lin_b,
                                                 float* __restrict__ out) {
    int idx = blockIdx.x * 256 + threadIdx.x;   // 24576 threads
    int n = idx / 3, o = idx - n * 3;
    float w0 = wsum[0] * (1.0f / NN), w1v = wsum[1] * (1.0f / NN);
    float mx = fmaxf(w0, w1v);
    float e0 = expf(w0 - mx), e1 = expf(w1v - mx);
    float beta0 = e0 / (e0 + e1), beta1 = e1 / (e0 + e1);
    const unsigned short* p0 = z0 + (size_t)n * DIM;
    const unsigned short* p1 = z1 + (size_t)n * DIM;
    float acc = 0.f;
    for (int dd = 0; dd < DIM; dd++)
        acc += (beta0 * bf2f(p0[dd]) + beta1 * bf2f(p1[dd])) * lin_w[dd * 3 + o];
    out[idx] = acc + lin_b[o];
}

// ---------------- launch ----------------
extern "C" void kernel_launch(void* const* d_in, const int* in_sizes, int n_in,
                              void* d_out, int out_size, void* d_ws, size_t ws_size,
                              hipStream_t stream) {
    const float* feat = (const float*)d_in[0];
    const int*   srcp[2]   = { (const int*)d_in[1], (const int*)d_in[4] };
    const int*   dstp[2]   = { (const int*)d_in[2], (const int*)d_in[5] };
    const float* transp[2] = { (const float*)d_in[3], (const float*)d_in[6] };
    const float* fcw[2]    = { (const float*)d_in[7], (const float*)d_in[8] };
    const float* sem_w1 = (const float*)d_in[9];
    const float* sem_b1 = (const float*)d_in[10];
    const float* sem_w2 = (const float*)d_in[11];
    const float* lin_w  = (const float*)d_in[12];
    const float* lin_b  = (const float*)d_in[13];
    float* out = (float*)d_out;

    char* ws = (char*)d_ws;
    const size_t MB = 1 << 20;
    const size_t KB = 1 << 10;
    if (ws_size < 57 * MB) return;
    unsigned short* Ch    = (unsigned short*)(ws);               //  8 MB
    unsigned short* Cl    = (unsigned short*)(ws + 8 * MB);      //  8 MB
    unsigned short* z0    = (unsigned short*)(ws + 16 * MB);     //  8 MB
    unsigned short* z1    = (unsigned short*)(ws + 24 * MB);     //  8 MB
    unsigned short* fH    = (unsigned short*)(ws + 32 * MB);     //  8 MB
    unsigned short* fL    = (unsigned short*)(ws + 40 * MB);     //  8 MB
    float*          e     = (float*)(ws + 48 * MB);              //  4 MB (NE_HALF*8)
    float*          vals  = (float*)(ws + 52 * MB);              // 512 KB
    int*            eid   = (int*)  (ws + 52 * MB + 512 * KB);   //  1 MB
    int*            ceid  = (int*)  (ws + 53 * MB + 512 * KB);   // 512 KB
    unsigned short* BhT   = (unsigned short*)(ws + 54 * MB);             // 512 KB
    unsigned short* BlT   = (unsigned short*)(ws + 54 * MB + 512 * KB);  // 512 KB
    unsigned short* W1hT  = (unsigned short*)(ws + 55 * MB);             // 128 KB
    unsigned short* W1lT  = (unsigned short*)(ws + 55 * MB + 128 * KB);  // 128 KB
    unsigned char*  keep  = (unsigned char*)(ws + 55 * MB + 256 * KB);   // 256 KB
    int*            counts = (int*) (ws + 55 * MB + 512 * KB);   // 32 KB
    int*            countsC= (int*) (ws + 55 * MB + 544 * KB);   // 32 KB (contiguous w/ counts)
    int*            offs   = (int*) (ws + 55 * MB + 576 * KB);   // 36 KB
    int*            cur    = (int*) (ws + 55 * MB + 612 * KB);   // 32 KB
    int*            coffs  = (int*) (ws + 55 * MB + 644 * KB);   // 36 KB
    int*            ccur   = (int*) (ws + 55 * MB + 680 * KB);   // 32 KB
    float*          wsum   = (float*)(ws + 55 * MB + 712 * KB);

    split_feat<<<(NN * DIM / 4) / 256, 256, 0, stream>>>(feat, fH, fL);
    split_w1t<<<dim3(4, 16), 256, 0, stream>>>(sem_w1, W1hT, W1lT);
    for (int c = 0; c < 2; c++) {
        unsigned short* z = c ? z1 : z0;
        hipMemsetAsync(counts, 0, 2 * NN * sizeof(int), stream);   // counts + countsC
        count_src<<<NE / 256, 256, 0, stream>>>(srcp[c], counts);
        count_src<<<NE_HALF / 256, 256, 0, stream>>>(srcp[c], countsC);  // canonical half only
        scan_offs<<<1, 256, 0, stream>>>(counts, offs, cur);
        scan_offs<<<1, 256, 0, stream>>>(countsC, coffs, ccur);
        scatter_src<<<NE / 256, 256, 0, stream>>>(srcp[c], cur, eid);
        scatter_src<<<NE_HALF / 256, 256, 0, stream>>>(srcp[c], ccur, ceid);
        split_w<<<dim3(16, 16), 256, 0, stream>>>(fcw[c], BhT, BlT);
        gemm_mfma<<<dim3(8, 64), 256, 0, stream>>>(fH, fL, BhT, BlT, Ch, Cl);
        edge_dots_csr<<<NN, 256, 0, stream>>>(Ch, Cl, coffs, ceid, dstp[c], transp[c], e, vals);
        row_thresh<<<NN, 128, 0, stream>>>(offs, eid, dstp[c], vals, keep);
        aggregate<<<NN, 256, 0, stream>>>(offs, eid, dstp[c], e, keep, Ch, z);
    }
    hipMemsetAsync(wsum, 0, 2 * sizeof(float), stream);
    sem_scores3<<<dim3(NN / 64, 2), 256, 0, stream>>>(z0, z1, W1hT, W1lT, sem_b1, sem_w2, wsum);
    final_out<<<(NN * 3) / 256, 256, 0, stream>>>(z0, z1, wsum, lin_w, lin_b, out);
}